// Round 2
// baseline (1144.663 us; speedup 1.0000x reference)
//
#include <hip/hip_runtime.h>

typedef unsigned int uint;
typedef __fp16 half2_t __attribute__((ext_vector_type(2)));

#define SEQ 512
#define BATCH 128
#define HID 128
#define NTAG 32
#define START_TAG 30
#define END_TAG 31

__device__ __forceinline__ float fdot2(uint a, uint b, float c) {
  return __builtin_amdgcn_fdot2(__builtin_bit_cast(half2_t, a),
                                __builtin_bit_cast(half2_t, b), c, false);
}
__device__ __forceinline__ uint packh2(float a, float b) {
  half2_t h = __builtin_amdgcn_cvt_pkrtz(a, b);
  return __builtin_bit_cast(uint, h);
}
__device__ __forceinline__ float frcp(float x) { return __builtin_amdgcn_rcpf(x); }
__device__ __forceinline__ float fsig(float x) { return frcp(1.f + __expf(-x)); }
__device__ __forceinline__ float ftanh(float x) { return 1.f - 2.f * frcp(1.f + __expf(2.f * x)); }

// ---------------------------------------------------------------------------
// Pack weights: wcat[d][gate][128 dw]: dw<64 -> pack(W_ih[g][2dw],[2dw+1]),
// dw>=64 -> pack(W_hh[g][2(dw-64)],[+1]). woutp[k][128 dw] similarly from
// W_out[k][0:128] then [128:256]. biasc[d][g] = b_ih+b_hh.
// ---------------------------------------------------------------------------
__global__ __launch_bounds__(256) void prep_kernel(
    const float* __restrict__ Wihf, const float* __restrict__ Whhf,
    const float* __restrict__ bihf, const float* __restrict__ bhhf,
    const float* __restrict__ Wihb, const float* __restrict__ Whhb,
    const float* __restrict__ bihb, const float* __restrict__ bhhb,
    const float* __restrict__ Wout,
    uint* __restrict__ wcat, uint* __restrict__ woutp, float* __restrict__ biasc)
{
  int idx = blockIdx.x * 256 + threadIdx.x;
  if (idx < 2 * 512 * 128) {
    int d = idx >> 16;
    int rem = idx & 65535;
    int g = rem >> 7;
    int dw = rem & 127;
    const float* Wih = d ? Wihb : Wihf;
    const float* Whh = d ? Whhb : Whhf;
    float a, b2;
    if (dw < 64) { a = Wih[g * 128 + 2 * dw]; b2 = Wih[g * 128 + 2 * dw + 1]; }
    else { int k = dw - 64; a = Whh[g * 128 + 2 * k]; b2 = Whh[g * 128 + 2 * k + 1]; }
    wcat[idx] = packh2(a, b2);
  }
  int i2 = idx - 2 * 512 * 128;
  if (i2 >= 0 && i2 < 32 * 128) {
    int k = i2 >> 7, dw = i2 & 127;
    float a, b2;
    if (dw < 64) { a = Wout[k * 256 + 2 * dw]; b2 = Wout[k * 256 + 2 * dw + 1]; }
    else { int j = dw - 64; a = Wout[k * 256 + 128 + 2 * j]; b2 = Wout[k * 256 + 128 + 2 * j + 1]; }
    woutp[i2] = packh2(a, b2);
  }
  int i3 = idx - (2 * 512 * 128 + 32 * 128);
  if (i3 >= 0 && i3 < 2 * 512) {
    int d = i3 >> 9, g = i3 & 511;
    biasc[i3] = d ? (bihb[g] + bhhb[g]) : (bihf[g] + bhhf[g]);
  }
}

// ---------------------------------------------------------------------------
// LSTM recurrence. One workgroup per (direction, batch element). 256 threads.
// Thread (wave w, lane l): hp = l>>5 selects x-half (0) or h-half (1) of the
// packed z vector; m = w*32 + (l&31) is the hidden unit; the thread computes
// partial dots for gates {m, 128+m, 256+m, 384+m} over its half, then
// shfl_xor(32) gives every lane the full i,f,g,o preacts for unit m.
// Weights live in VGPRs (64 uint4). One barrier per step, z double-buffered.
// ---------------------------------------------------------------------------
__global__ __launch_bounds__(256, 1) void lstm_kernel(
    const int* __restrict__ sentence, const float* __restrict__ embed,
    const uint* __restrict__ wcat, const float* __restrict__ biasc,
    const float* __restrict__ h0, const float* __restrict__ c0,
    uint* __restrict__ hh)
{
  const int wg = blockIdx.x;
  const int d = wg >> 7;
  const int b = wg & 127;
  const int tid = threadIdx.x;
  const int w = tid >> 6;
  const int lane = tid & 63;
  const int hp = lane >> 5;
  const int r = lane & 31;
  const int m = w * 32 + r;

  __shared__ __align__(16) uint zbuf[2][128];
  __shared__ int sent_s[SEQ];

  for (int i = tid; i < SEQ; i += 256) sent_s[i] = sentence[b * SEQ + i];

  const uint4* wc4 = (const uint4*)(wcat + (size_t)d * 512 * 128);
  uint4 wreg[4][16];
#pragma unroll
  for (int q = 0; q < 4; ++q) {
    const uint4* row = wc4 + (q * 128 + m) * 32 + hp * 16;
#pragma unroll
    for (int i = 0; i < 16; ++i) wreg[q][i] = row[i];
  }
  float bias[4];
#pragma unroll
  for (int q = 0; q < 4; ++q) bias[q] = biasc[d * 512 + q * 128 + m];

  float c = c0[(size_t)(d * BATCH + b) * HID + m];

  __syncthreads();  // sent_s ready
  {
    int s0 = d ? (SEQ - 1) : 0;
    int tok = sent_s[s0];
    if (tid < 64) {
      float2 xv = ((const float2*)(embed + (size_t)tok * HID))[tid];
      zbuf[0][tid] = packh2(xv.x, xv.y);
    } else if (tid < 128) {
      int k = tid - 64;
      float2 hv = ((const float2*)(h0 + (size_t)(d * BATCH + b) * HID))[k];
      zbuf[0][64 + k] = packh2(hv.x, hv.y);
    }
  }
  __syncthreads();

  int cur = 0;
  for (int t = 0; t < SEQ; ++t) {
    const int s = d ? (SEQ - 1 - t) : t;

    // prefetch next step's embedding pair (lanes hp==1, r even produce x dwords)
    float2 xpre = make_float2(0.f, 0.f);
    if ((t + 1 < SEQ) && hp == 1 && (r & 1) == 0) {
      int sn = d ? (SEQ - 2 - t) : (t + 1);
      int tok = sent_s[sn];
      xpre = ((const float2*)(embed + (size_t)tok * HID))[w * 16 + (r >> 1)];
    }

    float a0 = hp ? 0.f : bias[0];
    float a1 = hp ? 0.f : bias[1];
    float a2 = hp ? 0.f : bias[2];
    float a3 = hp ? 0.f : bias[3];
    const uint4* z4 = (const uint4*)(&zbuf[cur][hp * 64]);
#pragma unroll
    for (int i = 0; i < 16; ++i) {
      uint4 z = z4[i];
      a0 = fdot2(z.x, wreg[0][i].x, a0);
      a0 = fdot2(z.y, wreg[0][i].y, a0);
      a0 = fdot2(z.z, wreg[0][i].z, a0);
      a0 = fdot2(z.w, wreg[0][i].w, a0);
      a1 = fdot2(z.x, wreg[1][i].x, a1);
      a1 = fdot2(z.y, wreg[1][i].y, a1);
      a1 = fdot2(z.z, wreg[1][i].z, a1);
      a1 = fdot2(z.w, wreg[1][i].w, a1);
      a2 = fdot2(z.x, wreg[2][i].x, a2);
      a2 = fdot2(z.y, wreg[2][i].y, a2);
      a2 = fdot2(z.z, wreg[2][i].z, a2);
      a2 = fdot2(z.w, wreg[2][i].w, a2);
      a3 = fdot2(z.x, wreg[3][i].x, a3);
      a3 = fdot2(z.y, wreg[3][i].y, a3);
      a3 = fdot2(z.z, wreg[3][i].z, a3);
      a3 = fdot2(z.w, wreg[3][i].w, a3);
    }
    a0 += __shfl_xor(a0, 32);
    a1 += __shfl_xor(a1, 32);
    a2 += __shfl_xor(a2, 32);
    a3 += __shfl_xor(a3, 32);

    float ig = fsig(a0);
    float fg = fsig(a1);
    float gg = ftanh(a2);
    float og = fsig(a3);
    c = fg * c + ig * gg;
    float hv = og * ftanh(c);

    float hn = __shfl_xor(hv, 1);
    int nxt = cur ^ 1;
    if ((r & 1) == 0) {
      if (hp == 0) {
        uint pd = packh2(hv, hn);
        int dw = m >> 1;
        zbuf[nxt][64 + dw] = pd;
        hh[((size_t)(d * SEQ + s) * BATCH + b) * 64 + dw] = pd;
      } else if (t + 1 < SEQ) {
        zbuf[nxt][w * 16 + (r >> 1)] = packh2(xpre.x, xpre.y);
      }
    }
    __syncthreads();
    cur = nxt;
  }
}

// ---------------------------------------------------------------------------
// Output projection: feats[b,s,k] = [hf|hb] . Wout[k] + bout[k]
// Block handles 8 (b,s) rows x 32 k. h rows + Wout staged in LDS (Wout
// transposed so per-k reads are consecutive uint4 -> conflict-free).
// ---------------------------------------------------------------------------
__global__ __launch_bounds__(256) void outproj_kernel(
    const uint* __restrict__ hh, const uint* __restrict__ woutp,
    const float* __restrict__ bout, float* __restrict__ feats)
{
  __shared__ __align__(16) uint4 zrow[8][32];
  __shared__ __align__(16) uint4 wlds[32][32];
  int tid = threadIdx.x;
  for (int j = tid; j < 1024; j += 256) {
    int k = j >> 5, i = j & 31;
    wlds[i][k] = ((const uint4*)woutp)[j];
  }
  int rl = tid >> 5, q = tid & 31;
  int row = blockIdx.x * 8 + rl;
  int b = row >> 9, s = row & 511;
  const uint4* hf4 = (const uint4*)(hh + ((size_t)s * BATCH + b) * 64);
  const uint4* hb4 = (const uint4*)(hh + ((size_t)(SEQ + s) * BATCH + b) * 64);
  zrow[rl][q] = (q < 16) ? hf4[q] : hb4[q - 16];
  __syncthreads();
  int k = q;
  float acc = bout[k];
#pragma unroll
  for (int i = 0; i < 32; ++i) {
    uint4 z = zrow[rl][i];
    uint4 wv = wlds[i][k];
    acc = fdot2(z.x, wv.x, acc);
    acc = fdot2(z.y, wv.y, acc);
    acc = fdot2(z.z, wv.z, acc);
    acc = fdot2(z.w, wv.w, acc);
  }
  feats[(size_t)row * 32 + k] = acc;
}

// ---------------------------------------------------------------------------
// CRF numerator: per-batch wave; trans[prev,next] + emit + trans[last,END]
// ---------------------------------------------------------------------------
__global__ __launch_bounds__(64) void crf_num_kernel(
    const int* __restrict__ tags, const float* __restrict__ feats,
    const float* __restrict__ trans, float* __restrict__ num)
{
  int b = blockIdx.x, l = threadIdx.x;
  const int* tb = tags + b * SEQ;
  float acc = 0.f;
  for (int s = l; s < SEQ; s += 64) {
    int tg = tb[s];
    int pv = (s == 0) ? START_TAG : tb[s - 1];
    acc += trans[pv * NTAG + tg] + feats[((size_t)b * SEQ + s) * NTAG + tg];
  }
#pragma unroll
  for (int msk = 1; msk < 64; msk <<= 1) acc += __shfl_xor(acc, msk);
  if (l == 0) num[b] = acc + trans[tb[SEQ - 1] * NTAG + END_TAG];
}

// ---------------------------------------------------------------------------
// CRF denominator (forward algorithm). One wave per batch element.
// lane l: k = l&31 (next tag), hp = l>>5 selects prev half [hp*16, hp*16+16).
// trans[k][prev half] in registers; alpha in LDS; halves merged by shfl.
// ---------------------------------------------------------------------------
__global__ __launch_bounds__(64) void crf_den_kernel(
    const float* __restrict__ feats, const float* __restrict__ trans,
    float* __restrict__ den)
{
  int b = blockIdx.x, l = threadIdx.x;
  int k = l & 31, hp = l >> 5;
  float T[16];
#pragma unroll
  for (int p = 0; p < 16; ++p) T[p] = trans[k * NTAG + hp * 16 + p];
  __shared__ __align__(16) float alpha[32];
  if (l < 32) alpha[l] = (l == START_TAG) ? 0.f : -10000.f;
  __syncthreads();
  const float* fb = feats + (size_t)b * SEQ * NTAG;
  for (int s = 0; s < SEQ; ++s) {
    float fk = fb[s * NTAG + k];
    float4 av0 = ((const float4*)alpha)[hp * 4 + 0];
    float4 av1 = ((const float4*)alpha)[hp * 4 + 1];
    float4 av2 = ((const float4*)alpha)[hp * 4 + 2];
    float4 av3 = ((const float4*)alpha)[hp * 4 + 3];
    float v[16];
    v[0] = av0.x + T[0];  v[1] = av0.y + T[1];  v[2] = av0.z + T[2];  v[3] = av0.w + T[3];
    v[4] = av1.x + T[4];  v[5] = av1.y + T[5];  v[6] = av1.z + T[6];  v[7] = av1.w + T[7];
    v[8] = av2.x + T[8];  v[9] = av2.y + T[9];  v[10] = av2.z + T[10]; v[11] = av2.w + T[11];
    v[12] = av3.x + T[12]; v[13] = av3.y + T[13]; v[14] = av3.z + T[14]; v[15] = av3.w + T[15];
    float mx = v[0];
#pragma unroll
    for (int p = 1; p < 16; ++p) mx = fmaxf(mx, v[p]);
    float sm = 0.f;
#pragma unroll
    for (int p = 0; p < 16; ++p) sm += __expf(v[p] - mx);
    float m2 = __shfl_xor(mx, 32);
    float s2 = __shfl_xor(sm, 32);
    float M = fmaxf(mx, m2);
    float S = sm * __expf(mx - M) + s2 * __expf(m2 - M);
    float anew = M + __logf(S) + fk;
    __syncthreads();
    if (l < 32) alpha[k] = anew;
    __syncthreads();
  }
  float val = alpha[k] + trans[k * NTAG + END_TAG];
  float mm = val, ss = 1.f;
#pragma unroll
  for (int msk = 1; msk <= 16; msk <<= 1) {
    float m2 = __shfl_xor(mm, msk);
    float s2 = __shfl_xor(ss, msk);
    float M = fmaxf(mm, m2);
    ss = ss * __expf(mm - M) + s2 * __expf(m2 - M);
    mm = M;
  }
  if (l == 0) den[b] = mm + __logf(ss);
}

__global__ __launch_bounds__(128) void final_kernel(
    const float* __restrict__ num, const float* __restrict__ den,
    float* __restrict__ out)
{
  int tid = threadIdx.x;
  float v = num[tid] - den[tid];
#pragma unroll
  for (int msk = 1; msk < 64; msk <<= 1) v += __shfl_xor(v, msk);
  __shared__ float tmp[2];
  if ((tid & 63) == 0) tmp[tid >> 6] = v;
  __syncthreads();
  if (tid == 0) out[0] = (tmp[0] + tmp[1]) * (1.f / 128.f);
}

// ---------------------------------------------------------------------------
// Workspace layout (bytes):
//   wcat   @ 0        : 2*512*128*4   = 524288
//   woutp  @ 524288   : 32*128*4      = 16384
//   biasc  @ 540672   : 2*512*4       = 4096
//   num    @ 544768   : 512
//   den    @ 545280   : 512
//   hh     @ 1048576  : 2*512*128*64*4 = 33554432 (packed f16 h history)
//   feats  @ 34603008 : 128*512*32*4  = 8388608
//   total ~43 MB
// ---------------------------------------------------------------------------
extern "C" void kernel_launch(void* const* d_in, const int* in_sizes, int n_in,
                              void* d_out, int out_size, void* d_ws, size_t ws_size,
                              hipStream_t stream)
{
  const int* sentence = (const int*)d_in[0];
  const int* tags = (const int*)d_in[1];
  const float* embed = (const float*)d_in[2];
  const float* Wihf = (const float*)d_in[3];
  const float* Whhf = (const float*)d_in[4];
  const float* bihf = (const float*)d_in[5];
  const float* bhhf = (const float*)d_in[6];
  const float* Wihb = (const float*)d_in[7];
  const float* Whhb = (const float*)d_in[8];
  const float* bihb = (const float*)d_in[9];
  const float* bhhb = (const float*)d_in[10];
  const float* Wout = (const float*)d_in[11];
  const float* bout = (const float*)d_in[12];
  const float* trans = (const float*)d_in[13];
  const float* h0 = (const float*)d_in[14];
  const float* c0 = (const float*)d_in[15];
  float* out = (float*)d_out;

  char* ws = (char*)d_ws;
  uint* wcat = (uint*)(ws + 0);
  uint* woutp = (uint*)(ws + 524288);
  float* biasc = (float*)(ws + 540672);
  float* numb = (float*)(ws + 544768);
  float* denb = (float*)(ws + 545280);
  uint* hh = (uint*)(ws + 1048576);
  float* feats = (float*)(ws + 34603008);

  hipLaunchKernelGGL(prep_kernel, dim3(532), dim3(256), 0, stream,
                     Wihf, Whhf, bihf, bhhf, Wihb, Whhb, bihb, bhhb, Wout,
                     wcat, woutp, biasc);
  hipLaunchKernelGGL(lstm_kernel, dim3(256), dim3(256), 0, stream,
                     sentence, embed, wcat, biasc, h0, c0, hh);
  hipLaunchKernelGGL(outproj_kernel, dim3(8192), dim3(256), 0, stream,
                     hh, woutp, bout, feats);
  hipLaunchKernelGGL(crf_num_kernel, dim3(128), dim3(64), 0, stream,
                     tags, feats, trans, numb);
  hipLaunchKernelGGL(crf_den_kernel, dim3(128), dim3(64), 0, stream,
                     feats, trans, denb);
  hipLaunchKernelGGL(final_kernel, dim3(1), dim3(128), 0, stream,
                     numb, denb, out);
}

// Round 4
// 756.126 us; speedup vs baseline: 1.5139x; 1.5139x over previous
//
#include <hip/hip_runtime.h>

typedef unsigned int uint;
typedef __fp16 half2_t __attribute__((ext_vector_type(2)));

#define SEQ 512
#define BATCH 128
#define HID 128
#define NTAG 32
#define START_TAG 30
#define END_TAG 31

__device__ __forceinline__ float fdot2(uint a, uint b, float c) {
  return __builtin_amdgcn_fdot2(__builtin_bit_cast(half2_t, a),
                                __builtin_bit_cast(half2_t, b), c, false);
}
__device__ __forceinline__ uint packh2(float a, float b) {
  half2_t h = __builtin_amdgcn_cvt_pkrtz(a, b);
  return __builtin_bit_cast(uint, h);
}
__device__ __forceinline__ float frcp(float x) { return __builtin_amdgcn_rcpf(x); }
__device__ __forceinline__ float fsig(float x) { return frcp(1.f + __expf(-x)); }
__device__ __forceinline__ float ftanh(float x) { return 1.f - 2.f * frcp(1.f + __expf(2.f * x)); }
__device__ __forceinline__ float fexp2(float x) { return __builtin_amdgcn_exp2f(x); }
__device__ __forceinline__ float flog2(float x) { return __builtin_amdgcn_logf(x); }

// ---------------------------------------------------------------------------
// prep: pack W_ih -> wih[d][512g][64dw], W_hh -> whh[d][512g][64dw] (f16x2),
// W_out -> woutp (as before), biasc[d][g] = b_ih+b_hh (folded into gemmx).
// ---------------------------------------------------------------------------
__global__ __launch_bounds__(256) void prep_kernel(
    const float* __restrict__ Wihf, const float* __restrict__ Whhf,
    const float* __restrict__ bihf, const float* __restrict__ bhhf,
    const float* __restrict__ Wihb, const float* __restrict__ Whhb,
    const float* __restrict__ bihb, const float* __restrict__ bhhb,
    const float* __restrict__ Wout,
    uint* __restrict__ wih, uint* __restrict__ whh,
    uint* __restrict__ woutp, float* __restrict__ biasc)
{
  int idx = blockIdx.x * 256 + threadIdx.x;
  if (idx < 65536) {  // wih
    int d = idx >> 15, rem = idx & 32767;
    int g = rem >> 6, dw = rem & 63;
    const float* W = d ? Wihb : Wihf;
    wih[idx] = packh2(W[g * 128 + 2 * dw], W[g * 128 + 2 * dw + 1]);
  }
  int i2 = idx - 65536;
  if (i2 >= 0 && i2 < 65536) {  // whh
    int d = i2 >> 15, rem = i2 & 32767;
    int g = rem >> 6, dw = rem & 63;
    const float* W = d ? Whhb : Whhf;
    whh[i2] = packh2(W[g * 128 + 2 * dw], W[g * 128 + 2 * dw + 1]);
  }
  int i3 = idx - 131072;
  if (i3 >= 0 && i3 < 4096) {  // woutp
    int k = i3 >> 7, dw = i3 & 127;
    float a, b2;
    if (dw < 64) { a = Wout[k * 256 + 2 * dw]; b2 = Wout[k * 256 + 2 * dw + 1]; }
    else { int j = dw - 64; a = Wout[k * 256 + 128 + 2 * j]; b2 = Wout[k * 256 + 128 + 2 * j + 1]; }
    woutp[i3] = packh2(a, b2);
  }
  int i4 = idx - 135168;
  if (i4 >= 0 && i4 < 1024) {  // biasc
    int d = i4 >> 9, g = i4 & 511;
    biasc[i4] = d ? (bihb[g] + bhhb[g]) : (bihf[g] + bhhf[g]);
  }
}

// ---------------------------------------------------------------------------
// gemmx: gatex[tl][b][d][m-gates] = x_s . W_ih[g]^T + bias (f16-packed, 4
// gates per unit m as uint2). One chunk = 128 t-steps. Block: 32 b-rows
// (one s) x 128 gates (d, mg fixed; q=0..3). blk = d<<11 | sl<<4 | bt<<2 | mg.
// ---------------------------------------------------------------------------
__global__ __launch_bounds__(256) void gemmx_kernel(
    const int* __restrict__ sentence, const float* __restrict__ embed,
    const uint* __restrict__ wih, const float* __restrict__ biasc,
    uint* __restrict__ gatex, int chunk)
{
  int blk = blockIdx.x;
  int mg = blk & 3, bt = (blk >> 2) & 3, sl = (blk >> 4) & 127, d = blk >> 11;
  int t = chunk * 128 + sl;
  int s = d ? (511 - t) : t;
  __shared__ int tok[32];
  __shared__ __align__(16) uint xlds[32][64];
  __shared__ __align__(16) uint4 wlds[16][128];  // [j][q*32+mi]
  int tid = threadIdx.x;
  if (tid < 32) tok[tid] = sentence[(bt * 32 + tid) * SEQ + s];
  {
    int gl = tid >> 1, half = tid & 1;
    int q = gl >> 5, mi5 = gl & 31;
    const uint4* src = (const uint4*)(wih + ((size_t)d * 512 + q * 128 + mg * 32 + mi5) * 64) + half * 8;
#pragma unroll
    for (int jj = 0; jj < 8; ++jj) wlds[half * 8 + jj][gl] = src[jj];
  }
  __syncthreads();
  {
    int rw = tid >> 3, part = tid & 7;
    const float4* e4 = (const float4*)(embed + (size_t)tok[rw] * HID) + part * 4;
    float4 v0 = e4[0], v1 = e4[1], v2 = e4[2], v3 = e4[3];
    uint4 p0, p1;
    p0.x = packh2(v0.x, v0.y); p0.y = packh2(v0.z, v0.w);
    p0.z = packh2(v1.x, v1.y); p0.w = packh2(v1.z, v1.w);
    p1.x = packh2(v2.x, v2.y); p1.y = packh2(v2.z, v2.w);
    p1.z = packh2(v3.x, v3.y); p1.w = packh2(v3.z, v3.w);
    uint4* dst = (uint4*)&xlds[rw][part * 8];
    dst[0] = p0; dst[1] = p1;
  }
  __syncthreads();
  int mi = tid & 31, rg = tid >> 5;
  float acc[4][4];  // [row][q]
#pragma unroll
  for (int q = 0; q < 4; ++q) {
    float bq = biasc[d * 512 + q * 128 + mg * 32 + mi];
#pragma unroll
    for (int rr = 0; rr < 4; ++rr) acc[rr][q] = bq;
  }
#pragma unroll
  for (int j = 0; j < 16; ++j) {
    uint4 w0 = wlds[j][mi];
    uint4 w1 = wlds[j][32 + mi];
    uint4 w2 = wlds[j][64 + mi];
    uint4 w3 = wlds[j][96 + mi];
#pragma unroll
    for (int rr = 0; rr < 4; ++rr) {
      uint4 z = *(const uint4*)&xlds[rg * 4 + rr][j * 4];
      acc[rr][0] = fdot2(z.x, w0.x, acc[rr][0]);
      acc[rr][0] = fdot2(z.y, w0.y, acc[rr][0]);
      acc[rr][0] = fdot2(z.z, w0.z, acc[rr][0]);
      acc[rr][0] = fdot2(z.w, w0.w, acc[rr][0]);
      acc[rr][1] = fdot2(z.x, w1.x, acc[rr][1]);
      acc[rr][1] = fdot2(z.y, w1.y, acc[rr][1]);
      acc[rr][1] = fdot2(z.z, w1.z, acc[rr][1]);
      acc[rr][1] = fdot2(z.w, w1.w, acc[rr][1]);
      acc[rr][2] = fdot2(z.x, w2.x, acc[rr][2]);
      acc[rr][2] = fdot2(z.y, w2.y, acc[rr][2]);
      acc[rr][2] = fdot2(z.z, w2.z, acc[rr][2]);
      acc[rr][2] = fdot2(z.w, w2.w, acc[rr][2]);
      acc[rr][3] = fdot2(z.x, w3.x, acc[rr][3]);
      acc[rr][3] = fdot2(z.y, w3.y, acc[rr][3]);
      acc[rr][3] = fdot2(z.z, w3.z, acc[rr][3]);
      acc[rr][3] = fdot2(z.w, w3.w, acc[rr][3]);
    }
  }
#pragma unroll
  for (int rr = 0; rr < 4; ++rr) {
    int b = bt * 32 + rg * 4 + rr;
    uint2 o;
    o.x = packh2(acc[rr][0], acc[rr][1]);
    o.y = packh2(acc[rr][2], acc[rr][3]);
    *(uint2*)&gatex[(((size_t)sl * 128 + b) * 2 + d) * 256 + (mg * 32 + mi) * 2] = o;
  }
}

// ---------------------------------------------------------------------------
// LSTM recurrence, h-weights only (32 uint4 = 128 VGPRs/thread -> stays in
// arch VGPRs). One workgroup per (d,b); 128 steps per launch (chunk).
// h history in LDS, flushed to hh once per chunk; no vmem store in loop.
// ---------------------------------------------------------------------------
__global__ __launch_bounds__(256, 1) void lstm_kernel(
    const uint* __restrict__ gatex, const uint* __restrict__ whh,
    const float* __restrict__ h0, const float* __restrict__ c0,
    float* __restrict__ statec, uint* __restrict__ hh, int chunk)
{
  const int wg = blockIdx.x;
  const int d = wg >> 7, b = wg & 127;
  const int tid = threadIdx.x;
  const int w = tid >> 6, lane = tid & 63;
  const int hp = lane >> 5, r = lane & 31;
  const int m = w * 32 + r;

  __shared__ __align__(16) uint hist[128][64];

  const uint4* wh4 = (const uint4*)(whh + (size_t)d * 512 * 64);
  uint4 wreg[4][8];
#pragma unroll
  for (int q = 0; q < 4; ++q) {
    const uint4* row = wh4 + (q * 128 + m) * 16 + hp * 8;
#pragma unroll
    for (int i = 0; i < 8; ++i) wreg[q][i] = row[i];
  }

  float c = (chunk == 0) ? c0[(size_t)(d * 128 + b) * 128 + m]
                         : statec[(size_t)(d * 128 + b) * 128 + m];

  if (tid < 64) {
    if (chunk == 0) {
      float2 hv = ((const float2*)(h0 + (size_t)(d * 128 + b) * 128))[tid];
      hist[127][tid] = packh2(hv.x, hv.y);
    } else {
      int sprev = d ? (511 - (chunk * 128 - 1)) : (chunk * 128 - 1);
      hist[127][tid] = hh[((size_t)(d * 512 + sprev) * 128 + b) * 64 + tid];
    }
  }
  const uint* gx0 = gatex + (size_t)b * 512 + d * 256 + m * 2;  // + tl*128*512
  uint2 gx = *(const uint2*)(gx0);
  __syncthreads();

  for (int tl = 0; tl < 128; ++tl) {
    uint2 gxn = gx;
    if (tl < 127) gxn = *(const uint2*)(gx0 + (size_t)(tl + 1) * 65536);

    float a0 = 0.f, a1 = 0.f, a2 = 0.f, a3 = 0.f;
    const uint4* z4 = (const uint4*)(&hist[(tl + 127) & 127][hp * 32]);
#pragma unroll
    for (int i = 0; i < 8; ++i) {
      uint4 z = z4[i];
      a0 = fdot2(z.x, wreg[0][i].x, a0);
      a0 = fdot2(z.y, wreg[0][i].y, a0);
      a0 = fdot2(z.z, wreg[0][i].z, a0);
      a0 = fdot2(z.w, wreg[0][i].w, a0);
      a1 = fdot2(z.x, wreg[1][i].x, a1);
      a1 = fdot2(z.y, wreg[1][i].y, a1);
      a1 = fdot2(z.z, wreg[1][i].z, a1);
      a1 = fdot2(z.w, wreg[1][i].w, a1);
      a2 = fdot2(z.x, wreg[2][i].x, a2);
      a2 = fdot2(z.y, wreg[2][i].y, a2);
      a2 = fdot2(z.z, wreg[2][i].z, a2);
      a2 = fdot2(z.w, wreg[2][i].w, a2);
      a3 = fdot2(z.x, wreg[3][i].x, a3);
      a3 = fdot2(z.y, wreg[3][i].y, a3);
      a3 = fdot2(z.z, wreg[3][i].z, a3);
      a3 = fdot2(z.w, wreg[3][i].w, a3);
    }
    a0 += __shfl_xor(a0, 32);
    a1 += __shfl_xor(a1, 32);
    a2 += __shfl_xor(a2, 32);
    a3 += __shfl_xor(a3, 32);

    half2_t g01 = __builtin_bit_cast(half2_t, gx.x);
    half2_t g23 = __builtin_bit_cast(half2_t, gx.y);
    a0 += (float)g01[0];
    a1 += (float)g01[1];
    a2 += (float)g23[0];
    a3 += (float)g23[1];

    float ig = fsig(a0);
    float fg = fsig(a1);
    float gg = ftanh(a2);
    float og = fsig(a3);
    c = fg * c + ig * gg;
    float hv = og * ftanh(c);

    float hn = __shfl_xor(hv, 1);
    if (hp == 0 && (r & 1) == 0) hist[tl][m >> 1] = packh2(hv, hn);
    gx = gxn;
    __syncthreads();
  }

  statec[(size_t)(d * 128 + b) * 128 + m] = c;

  int base = chunk * 128;
  for (int i = tid; i < 2048; i += 256) {
    int sl = i >> 4, q4 = i & 15;
    int s = d ? (511 - (base + sl)) : (base + sl);
    *(uint4*)(&hh[((size_t)(d * 512 + s) * 128 + b) * 64 + q4 * 4]) =
        *(const uint4*)(&hist[sl][q4 * 4]);
  }
}

// ---------------------------------------------------------------------------
// Output projection (unchanged, proven): feats[b,s,k] = [hf|hb].Wout[k]+bout
// ---------------------------------------------------------------------------
__global__ __launch_bounds__(256) void outproj_kernel(
    const uint* __restrict__ hh, const uint* __restrict__ woutp,
    const float* __restrict__ bout, float* __restrict__ feats)
{
  __shared__ __align__(16) uint4 zrow[8][32];
  __shared__ __align__(16) uint4 wlds[32][32];
  int tid = threadIdx.x;
  for (int j = tid; j < 1024; j += 256) {
    int k = j >> 5, i = j & 31;
    wlds[i][k] = ((const uint4*)woutp)[j];
  }
  int rl = tid >> 5, q = tid & 31;
  int row = blockIdx.x * 8 + rl;
  int b = row >> 9, s = row & 511;
  const uint4* hf4 = (const uint4*)(hh + ((size_t)s * BATCH + b) * 64);
  const uint4* hb4 = (const uint4*)(hh + ((size_t)(SEQ + s) * BATCH + b) * 64);
  zrow[rl][q] = (q < 16) ? hf4[q] : hb4[q - 16];
  __syncthreads();
  int k = q;
  float acc = bout[k];
#pragma unroll
  for (int i = 0; i < 32; ++i) {
    uint4 z = zrow[rl][i];
    uint4 wv = wlds[i][k];
    acc = fdot2(z.x, wv.x, acc);
    acc = fdot2(z.y, wv.y, acc);
    acc = fdot2(z.z, wv.z, acc);
    acc = fdot2(z.w, wv.w, acc);
  }
  feats[(size_t)row * 32 + k] = acc;
}

// ---------------------------------------------------------------------------
// CRF numerator
// ---------------------------------------------------------------------------
__global__ __launch_bounds__(64) void crf_num_kernel(
    const int* __restrict__ tags, const float* __restrict__ feats,
    const float* __restrict__ trans, float* __restrict__ num)
{
  int b = blockIdx.x, l = threadIdx.x;
  const int* tb = tags + b * SEQ;
  float acc = 0.f;
  for (int s = l; s < SEQ; s += 64) {
    int tg = tb[s];
    int pv = (s == 0) ? START_TAG : tb[s - 1];
    acc += trans[pv * NTAG + tg] + feats[((size_t)b * SEQ + s) * NTAG + tg];
  }
#pragma unroll
  for (int msk = 1; msk < 64; msk <<= 1) acc += __shfl_xor(acc, msk);
  if (l == 0) num[b] = acc + trans[tb[SEQ - 1] * NTAG + END_TAG];
}

// ---------------------------------------------------------------------------
// CRF denominator: shfl-exchanged alpha, base-2 domain, running-offset C
// (lane-0 alpha; cross-tag spread is bounded by feat+log2(K) so exp2 args
// stay within +-~30). No LDS, no barriers, no per-step max tree.
// ---------------------------------------------------------------------------
__global__ __launch_bounds__(64) void crf_den_kernel(
    const float* __restrict__ feats, const float* __restrict__ trans,
    float* __restrict__ den)
{
  const float L2E = 1.4426950408889634f, LN2 = 0.6931471805599453f;
  int b = blockIdx.x, l = threadIdx.x;
  int k = l & 31, hp = l >> 5;
  float T[16];
#pragma unroll
  for (int p = 0; p < 16; ++p) T[p] = trans[k * NTAG + hp * 16 + p] * L2E;
  float tEnd = trans[k * NTAG + END_TAG] * L2E;
  const float* fb = feats + (size_t)b * SEQ * NTAG;
  // exact step 0: only START is finite in the init alpha
  float A = (trans[k * NTAG + START_TAG] + fb[k]) * L2E;
  float fk = fb[NTAG + k];  // s = 1
  for (int s = 1; s < SEQ; ++s) {
    float fkn = (s + 1 < SEQ) ? fb[(s + 1) * NTAG + k] : 0.f;
    float C = __shfl(A, 0);
    float e[16];
#pragma unroll
    for (int p = 0; p < 16; ++p)
      e[p] = fexp2(__shfl(A, hp * 16 + p) - C + T[p]);
    float s01 = e[0] + e[1], s23 = e[2] + e[3];
    float s45 = e[4] + e[5], s67 = e[6] + e[7];
    float s89 = e[8] + e[9], sab = e[10] + e[11];
    float scd = e[12] + e[13], sef = e[14] + e[15];
    float q0 = s01 + s23, q1 = s45 + s67, q2 = s89 + sab, q3 = scd + sef;
    float sm = (q0 + q1) + (q2 + q3);
    float S = sm + __shfl_xor(sm, 32);
    A = C + flog2(S) + fk * L2E;
    fk = fkn;
  }
  float wv = A + tEnd;
  float C2 = __shfl(wv, 0);
  float e2 = fexp2(wv - C2);
#pragma unroll
  for (int msk = 1; msk <= 16; msk <<= 1) e2 += __shfl_xor(e2, msk);
  if (l == 0) den[b] = (C2 + flog2(e2)) * LN2;
}

__global__ __launch_bounds__(128) void final_kernel(
    const float* __restrict__ num, const float* __restrict__ den,
    float* __restrict__ out)
{
  int tid = threadIdx.x;
  float v = num[tid] - den[tid];
#pragma unroll
  for (int msk = 1; msk < 64; msk <<= 1) v += __shfl_xor(v, msk);
  __shared__ float tmp[2];
  if ((tid & 63) == 0) tmp[tid >> 6] = v;
  __syncthreads();
  if (tid == 0) out[0] = (tmp[0] + tmp[1]) * (1.f / 128.f);
}

// ---------------------------------------------------------------------------
// Workspace layout (bytes):
//   wih    @ 0        : 262144
//   whh    @ 262144   : 262144
//   woutp  @ 524288   : 16384
//   biasc  @ 540672   : 4096
//   numb   @ 544768   : 512
//   denb   @ 545280   : 512
//   statec @ 545792   : 131072
//   hh     @ 1048576  : 33554432   (packed f16 h history, both dirs)
//   gatex  @ 34603008 : 33554432   (one 128-step chunk of x-gates, f16)
//   feats  @ 34603008 : 8388608    (overlays gatex; written after last lstm)
//   total ~68 MB
// ---------------------------------------------------------------------------
extern "C" void kernel_launch(void* const* d_in, const int* in_sizes, int n_in,
                              void* d_out, int out_size, void* d_ws, size_t ws_size,
                              hipStream_t stream)
{
  const int* sentence = (const int*)d_in[0];
  const int* tags = (const int*)d_in[1];
  const float* embed = (const float*)d_in[2];
  const float* Wihf = (const float*)d_in[3];
  const float* Whhf = (const float*)d_in[4];
  const float* bihf = (const float*)d_in[5];
  const float* bhhf = (const float*)d_in[6];
  const float* Wihb = (const float*)d_in[7];
  const float* Whhb = (const float*)d_in[8];
  const float* bihb = (const float*)d_in[9];
  const float* bhhb = (const float*)d_in[10];
  const float* Wout = (const float*)d_in[11];
  const float* bout = (const float*)d_in[12];
  const float* trans = (const float*)d_in[13];
  const float* h0 = (const float*)d_in[14];
  const float* c0 = (const float*)d_in[15];
  float* out = (float*)d_out;

  char* ws = (char*)d_ws;
  uint* wih = (uint*)(ws + 0);
  uint* whh = (uint*)(ws + 262144);
  uint* woutp = (uint*)(ws + 524288);
  float* biasc = (float*)(ws + 540672);
  float* numb = (float*)(ws + 544768);
  float* denb = (float*)(ws + 545280);
  float* statec = (float*)(ws + 545792);
  uint* hh = (uint*)(ws + 1048576);
  uint* gatex = (uint*)(ws + 34603008);
  float* feats = (float*)(ws + 34603008);

  hipLaunchKernelGGL(prep_kernel, dim3(532), dim3(256), 0, stream,
                     Wihf, Whhf, bihf, bhhf, Wihb, Whhb, bihb, bhhb, Wout,
                     wih, whh, woutp, biasc);
  for (int c = 0; c < 4; ++c) {
    hipLaunchKernelGGL(gemmx_kernel, dim3(4096), dim3(256), 0, stream,
                       sentence, embed, wih, biasc, gatex, c);
    hipLaunchKernelGGL(lstm_kernel, dim3(256), dim3(256), 0, stream,
                       gatex, whh, h0, c0, statec, hh, c);
  }
  hipLaunchKernelGGL(outproj_kernel, dim3(8192), dim3(256), 0, stream,
                     hh, woutp, bout, feats);
  hipLaunchKernelGGL(crf_num_kernel, dim3(128), dim3(64), 0, stream,
                     tags, feats, trans, numb);
  hipLaunchKernelGGL(crf_den_kernel, dim3(128), dim3(64), 0, stream,
                     feats, trans, denb);
  hipLaunchKernelGGL(final_kernel, dim3(1), dim3(128), 0, stream,
                     numb, denb, out);
}

// Round 5
// 671.258 us; speedup vs baseline: 1.7052x; 1.1264x over previous
//
#include <hip/hip_runtime.h>

typedef unsigned int uint;
typedef __fp16 half2_t __attribute__((ext_vector_type(2)));
typedef __fp16 half8_t __attribute__((ext_vector_type(8)));
typedef float floatx4 __attribute__((ext_vector_type(4)));

#define SEQ 512
#define BATCH 128
#define HID 128
#define NTAG 32
#define START_TAG 30
#define END_TAG 31

__device__ __forceinline__ float fdot2(uint a, uint b, float c) {
  return __builtin_amdgcn_fdot2(__builtin_bit_cast(half2_t, a),
                                __builtin_bit_cast(half2_t, b), c, false);
}
__device__ __forceinline__ uint packh2(float a, float b) {
  half2_t h = __builtin_amdgcn_cvt_pkrtz(a, b);
  return __builtin_bit_cast(uint, h);
}
__device__ __forceinline__ float frcp(float x) { return __builtin_amdgcn_rcpf(x); }
__device__ __forceinline__ float fsig(float x) { return frcp(1.f + __expf(-x)); }
__device__ __forceinline__ float ftanh(float x) { return 1.f - 2.f * frcp(1.f + __expf(2.f * x)); }
__device__ __forceinline__ float fexp2(float x) { return __builtin_amdgcn_exp2f(x); }
__device__ __forceinline__ float flog2(float x) { return __builtin_amdgcn_logf(x); }

// ---------------------------------------------------------------------------
// prep:
//  wihI[d][n=4m+q][128k] f16 rows (gate-interleaved for MFMA B / lstm uint2)
//  whh [d][g=q*128+m][64dw] f16x2 (for lstm dot2, unchanged)
//  woutp (outproj, unchanged), biasI[d][n=4m+q] = b_ih+b_hh
// total items 65536+65536+4096+1024 = 136192 = 532*256
// ---------------------------------------------------------------------------
__global__ __launch_bounds__(256) void prep_kernel(
    const float* __restrict__ Wihf, const float* __restrict__ Whhf,
    const float* __restrict__ bihf, const float* __restrict__ bhhf,
    const float* __restrict__ Wihb, const float* __restrict__ Whhb,
    const float* __restrict__ bihb, const float* __restrict__ bhhb,
    const float* __restrict__ Wout,
    uint* __restrict__ wihI, uint* __restrict__ whh,
    uint* __restrict__ woutp, float* __restrict__ biasI)
{
  int idx = blockIdx.x * 256 + threadIdx.x;
  if (idx < 65536) {  // wihI, gate-interleaved rows
    int d = idx >> 15, rem = idx & 32767;
    int n = rem >> 6, dw = rem & 63;
    int m = n >> 2, q = n & 3;
    int g = q * 128 + m;
    const float* W = d ? Wihb : Wihf;
    wihI[idx] = packh2(W[g * 128 + 2 * dw], W[g * 128 + 2 * dw + 1]);
  }
  int i2 = idx - 65536;
  if (i2 >= 0 && i2 < 65536) {  // whh
    int d = i2 >> 15, rem = i2 & 32767;
    int g = rem >> 6, dw = rem & 63;
    const float* W = d ? Whhb : Whhf;
    whh[i2] = packh2(W[g * 128 + 2 * dw], W[g * 128 + 2 * dw + 1]);
  }
  int i3 = idx - 131072;
  if (i3 >= 0 && i3 < 4096) {  // woutp
    int k = i3 >> 7, dw = i3 & 127;
    float a, b2;
    if (dw < 64) { a = Wout[k * 256 + 2 * dw]; b2 = Wout[k * 256 + 2 * dw + 1]; }
    else { int j = dw - 64; a = Wout[k * 256 + 128 + 2 * j]; b2 = Wout[k * 256 + 128 + 2 * j + 1]; }
    woutp[i3] = packh2(a, b2);
  }
  int i4 = idx - 135168;
  if (i4 >= 0 && i4 < 1024) {  // biasI (interleaved)
    int d = i4 >> 9, n = i4 & 511;
    int g = (n & 3) * 128 + (n >> 2);
    biasI[i4] = d ? (bihb[g] + bhhb[g]) : (bihf[g] + bhhf[g]);
  }
}

// ---------------------------------------------------------------------------
// gemmx (MFMA): per (chunk,dir): C[16384 rows=(tl,b)][512 gates n=4m+q]
//   = embed[tok] (f32->f16) . wihI^T, +bias, stored f16.
// Block = (tl, nb, d): 128 rows (all b of one tl) x 128 cols. 4 waves,
// 64x64 wave tiles, frags straight from global (embed L3-hot, wihI L2-hot).
// blk = tl | nb<<7 | d<<9 ; grid 1024/chunk.
// ---------------------------------------------------------------------------
__global__ __launch_bounds__(256, 2) void gemmx_kernel(
    const int* __restrict__ sentence, const float* __restrict__ embed,
    const uint* __restrict__ wihI, const float* __restrict__ biasI,
    uint* __restrict__ gatex, int chunk)
{
  int blk = blockIdx.x;
  int tl = blk & 127, nb = (blk >> 7) & 3, d = blk >> 9;
  int t = chunk * 128 + tl;
  int s = d ? (511 - t) : t;
  __shared__ int tok[128];
  int tid = threadIdx.x;
  if (tid < 128) tok[tid] = sentence[tid * SEQ + s];
  __syncthreads();

  int w = tid >> 6, lane = tid & 63;
  int q = lane >> 4, r = lane & 15;
  int wr = w >> 1, wc = w & 1;
  int r0 = wr * 64;
  int c0 = nb * 128 + wc * 64;

  floatx4 acc[4][4];
#pragma unroll
  for (int i = 0; i < 4; ++i)
#pragma unroll
    for (int j = 0; j < 4; ++j) acc[i][j] = (floatx4){0.f, 0.f, 0.f, 0.f};

  const float4* aptr[4];
#pragma unroll
  for (int i = 0; i < 4; ++i)
    aptr[i] = (const float4*)(embed + (size_t)tok[r0 + i * 16 + r] * HID) + q * 2;
  const uint4* bptr[4];
#pragma unroll
  for (int j = 0; j < 4; ++j)
    bptr[j] = (const uint4*)(wihI + ((size_t)d * 512 + c0 + j * 16 + r) * 64) + q;

#pragma unroll
  for (int kc = 0; kc < 4; ++kc) {
    half8_t af[4], bf[4];
#pragma unroll
    for (int i = 0; i < 4; ++i) {
      float4 x0 = aptr[i][kc * 8];
      float4 x1 = aptr[i][kc * 8 + 1];
      uint4 u;
      u.x = packh2(x0.x, x0.y); u.y = packh2(x0.z, x0.w);
      u.z = packh2(x1.x, x1.y); u.w = packh2(x1.z, x1.w);
      af[i] = __builtin_bit_cast(half8_t, u);
    }
#pragma unroll
    for (int j = 0; j < 4; ++j)
      bf[j] = __builtin_bit_cast(half8_t, bptr[j][kc * 4]);
#pragma unroll
    for (int i = 0; i < 4; ++i)
#pragma unroll
      for (int j = 0; j < 4; ++j)
        acc[i][j] = __builtin_amdgcn_mfma_f32_16x16x32_f16(af[i], bf[j], acc[i][j], 0, 0, 0);
  }

  __fp16* gat = ((__fp16*)gatex) + (size_t)d * 16384 * 512;
#pragma unroll
  for (int j = 0; j < 4; ++j) {
    int n = c0 + j * 16 + r;
    float bb = biasI[d * 512 + n];
#pragma unroll
    for (int i = 0; i < 4; ++i) {
      int rb = r0 + i * 16 + q * 4;
#pragma unroll
      for (int reg = 0; reg < 4; ++reg) {
        float v = acc[i][j][reg] + bb;
        gat[((size_t)(tl * 128 + rb + reg)) * 512 + n] = (__fp16)v;
      }
    }
  }
}

// ---------------------------------------------------------------------------
// LSTM recurrence, h-weights only (32 uint4 = 128 VGPRs/thread). One WG per
// (d,b); 128 steps per launch (chunk). h history in LDS, flushed once.
// gatex layout: f16 [d][tl*128+b][n=4m+q] -> per-thread uint2 at 4m.
// ---------------------------------------------------------------------------
__global__ __launch_bounds__(256, 1) void lstm_kernel(
    const uint* __restrict__ gatex, const uint* __restrict__ whh,
    const float* __restrict__ h0, const float* __restrict__ c0,
    float* __restrict__ statec, uint* __restrict__ hh, int chunk)
{
  const int wg = blockIdx.x;
  const int d = wg >> 7, b = wg & 127;
  const int tid = threadIdx.x;
  const int w = tid >> 6, lane = tid & 63;
  const int hp = lane >> 5, r = lane & 31;
  const int m = w * 32 + r;

  __shared__ __align__(16) uint hist[128][64];

  const uint4* wh4 = (const uint4*)(whh + (size_t)d * 512 * 64);
  uint4 wreg[4][8];
#pragma unroll
  for (int q = 0; q < 4; ++q) {
    const uint4* row = wh4 + (q * 128 + m) * 16 + hp * 8;
#pragma unroll
    for (int i = 0; i < 8; ++i) wreg[q][i] = row[i];
  }

  float c = (chunk == 0) ? c0[(size_t)(d * 128 + b) * 128 + m]
                         : statec[(size_t)(d * 128 + b) * 128 + m];

  if (tid < 64) {
    if (chunk == 0) {
      float2 hv = ((const float2*)(h0 + (size_t)(d * 128 + b) * 128))[tid];
      hist[127][tid] = packh2(hv.x, hv.y);
    } else {
      int sprev = d ? (511 - (chunk * 128 - 1)) : (chunk * 128 - 1);
      hist[127][tid] = hh[((size_t)(d * 512 + sprev) * 128 + b) * 64 + tid];
    }
  }
  const uint* gx0 = gatex + (size_t)d * 4194304 + (size_t)b * 256 + 2 * m;
  uint2 gx = *(const uint2*)(gx0);
  __syncthreads();

  for (int tl = 0; tl < 128; ++tl) {
    uint2 gxn = gx;
    if (tl < 127) gxn = *(const uint2*)(gx0 + (size_t)(tl + 1) * 32768);

    float a0 = 0.f, a1 = 0.f, a2 = 0.f, a3 = 0.f;
    const uint4* z4 = (const uint4*)(&hist[(tl + 127) & 127][hp * 32]);
#pragma unroll
    for (int i = 0; i < 8; ++i) {
      uint4 z = z4[i];
      a0 = fdot2(z.x, wreg[0][i].x, a0);
      a0 = fdot2(z.y, wreg[0][i].y, a0);
      a0 = fdot2(z.z, wreg[0][i].z, a0);
      a0 = fdot2(z.w, wreg[0][i].w, a0);
      a1 = fdot2(z.x, wreg[1][i].x, a1);
      a1 = fdot2(z.y, wreg[1][i].y, a1);
      a1 = fdot2(z.z, wreg[1][i].z, a1);
      a1 = fdot2(z.w, wreg[1][i].w, a1);
      a2 = fdot2(z.x, wreg[2][i].x, a2);
      a2 = fdot2(z.y, wreg[2][i].y, a2);
      a2 = fdot2(z.z, wreg[2][i].z, a2);
      a2 = fdot2(z.w, wreg[2][i].w, a2);
      a3 = fdot2(z.x, wreg[3][i].x, a3);
      a3 = fdot2(z.y, wreg[3][i].y, a3);
      a3 = fdot2(z.z, wreg[3][i].z, a3);
      a3 = fdot2(z.w, wreg[3][i].w, a3);
    }
    a0 += __shfl_xor(a0, 32);
    a1 += __shfl_xor(a1, 32);
    a2 += __shfl_xor(a2, 32);
    a3 += __shfl_xor(a3, 32);

    half2_t g01 = __builtin_bit_cast(half2_t, gx.x);
    half2_t g23 = __builtin_bit_cast(half2_t, gx.y);
    a0 += (float)g01[0];
    a1 += (float)g01[1];
    a2 += (float)g23[0];
    a3 += (float)g23[1];

    float ig = fsig(a0);
    float fg = fsig(a1);
    float gg = ftanh(a2);
    float og = fsig(a3);
    c = fg * c + ig * gg;
    float hv = og * ftanh(c);

    float hn = __shfl_xor(hv, 1);
    if (hp == 0 && (r & 1) == 0) hist[tl][m >> 1] = packh2(hv, hn);
    gx = gxn;
    __syncthreads();
  }

  statec[(size_t)(d * 128 + b) * 128 + m] = c;

  int base = chunk * 128;
  for (int i = tid; i < 2048; i += 256) {
    int sl = i >> 4, q4 = i & 15;
    int s = d ? (511 - (base + sl)) : (base + sl);
    *(uint4*)(&hh[((size_t)(d * 512 + s) * 128 + b) * 64 + q4 * 4]) =
        *(const uint4*)(&hist[sl][q4 * 4]);
  }
}

// ---------------------------------------------------------------------------
// Output projection: feats[b,s,k] = [hf|hb] . Wout[k] + bout[k]
// ---------------------------------------------------------------------------
__global__ __launch_bounds__(256) void outproj_kernel(
    const uint* __restrict__ hh, const uint* __restrict__ woutp,
    const float* __restrict__ bout, float* __restrict__ feats)
{
  __shared__ __align__(16) uint4 zrow[8][32];
  __shared__ __align__(16) uint4 wlds[32][32];
  int tid = threadIdx.x;
  for (int j = tid; j < 1024; j += 256) {
    int k = j >> 5, i = j & 31;
    wlds[i][k] = ((const uint4*)woutp)[j];
  }
  int rl = tid >> 5, q = tid & 31;
  int row = blockIdx.x * 8 + rl;
  int b = row >> 9, s = row & 511;
  const uint4* hf4 = (const uint4*)(hh + ((size_t)s * BATCH + b) * 64);
  const uint4* hb4 = (const uint4*)(hh + ((size_t)(SEQ + s) * BATCH + b) * 64);
  zrow[rl][q] = (q < 16) ? hf4[q] : hb4[q - 16];
  __syncthreads();
  int k = q;
  float acc = bout[k];
#pragma unroll
  for (int i = 0; i < 32; ++i) {
    uint4 z = zrow[rl][i];
    uint4 wv = wlds[i][k];
    acc = fdot2(z.x, wv.x, acc);
    acc = fdot2(z.y, wv.y, acc);
    acc = fdot2(z.z, wv.z, acc);
    acc = fdot2(z.w, wv.w, acc);
  }
  feats[(size_t)row * 32 + k] = acc;
}

// ---------------------------------------------------------------------------
// CRF numerator
// ---------------------------------------------------------------------------
__global__ __launch_bounds__(64) void crf_num_kernel(
    const int* __restrict__ tags, const float* __restrict__ feats,
    const float* __restrict__ trans, float* __restrict__ num)
{
  int b = blockIdx.x, l = threadIdx.x;
  const int* tb = tags + b * SEQ;
  float acc = 0.f;
  for (int s = l; s < SEQ; s += 64) {
    int tg = tb[s];
    int pv = (s == 0) ? START_TAG : tb[s - 1];
    acc += trans[pv * NTAG + tg] + feats[((size_t)b * SEQ + s) * NTAG + tg];
  }
#pragma unroll
  for (int msk = 1; msk < 64; msk <<= 1) acc += __shfl_xor(acc, msk);
  if (l == 0) num[b] = acc + trans[tb[SEQ - 1] * NTAG + END_TAG];
}

// ---------------------------------------------------------------------------
// CRF denominator: one wave/batch. Per step: E=2^(A-C) (1 exp2), sum via
// 16 shfl+FMA against precomputed 2^T, log2. feats prefetched 8 steps ahead
// in a register ring (covers ~1600 cyc of HBM latency).
// ---------------------------------------------------------------------------
__global__ __launch_bounds__(64) void crf_den_kernel(
    const float* __restrict__ feats, const float* __restrict__ trans,
    float* __restrict__ den)
{
  const float L2E = 1.4426950408889634f, LN2 = 0.6931471805599453f;
  int b = blockIdx.x, l = threadIdx.x;
  int k = l & 31, hp = l >> 5;
  float pT[16];
#pragma unroll
  for (int p = 0; p < 16; ++p) pT[p] = fexp2(trans[k * NTAG + hp * 16 + p] * L2E);
  float tEnd = trans[k * NTAG + END_TAG] * L2E;
  const float* fb = feats + (size_t)b * SEQ * NTAG;
  // exact step 0: only START is finite in the init alpha
  float A = (trans[k * NTAG + START_TAG] + fb[k]) * L2E;
  float ring[8];
#pragma unroll
  for (int j = 0; j < 8; ++j) ring[j] = fb[(1 + j) * NTAG + k];
  // NOTE: ring reloads below read up to row 519 (~1 KB past feats) — lands in
  // the gatex workspace region, unused values.
  for (int tt = 0; tt < 64; ++tt) {
#pragma unroll
    for (int j = 0; j < 8; ++j) {
      int t = 1 + tt * 8 + j;
      if (t <= 511) {
        float fk = ring[j];
        ring[j] = fb[(t + 8) * NTAG + k];
        float C = __shfl(A, 0);
        float E = fexp2(A - C);
        float s0 = 0.f, s1 = 0.f, s2 = 0.f, s3 = 0.f;
#pragma unroll
        for (int p = 0; p < 16; p += 4) {
          s0 = fmaf(__shfl(E, hp * 16 + p + 0), pT[p + 0], s0);
          s1 = fmaf(__shfl(E, hp * 16 + p + 1), pT[p + 1], s1);
          s2 = fmaf(__shfl(E, hp * 16 + p + 2), pT[p + 2], s2);
          s3 = fmaf(__shfl(E, hp * 16 + p + 3), pT[p + 3], s3);
        }
        float sm = (s0 + s1) + (s2 + s3);
        float S = sm + __shfl_xor(sm, 32);
        A = C + flog2(S) + fk * L2E;
      }
    }
  }
  float wv = A + tEnd;
  float C2 = __shfl(wv, 0);
  float e2 = fexp2(wv - C2);
#pragma unroll
  for (int msk = 1; msk <= 16; msk <<= 1) e2 += __shfl_xor(e2, msk);
  if (l == 0) den[b] = (C2 + flog2(e2)) * LN2;
}

__global__ __launch_bounds__(128) void final_kernel(
    const float* __restrict__ num, const float* __restrict__ den,
    float* __restrict__ out)
{
  int tid = threadIdx.x;
  float v = num[tid] - den[tid];
#pragma unroll
  for (int msk = 1; msk < 64; msk <<= 1) v += __shfl_xor(v, msk);
  __shared__ float tmp[2];
  if ((tid & 63) == 0) tmp[tid >> 6] = v;
  __syncthreads();
  if (tid == 0) out[0] = (tmp[0] + tmp[1]) * (1.f / 128.f);
}

// ---------------------------------------------------------------------------
// Workspace layout (bytes) — identical footprint to R4 (~65 MB):
//   wihI   @ 0        : 262144
//   whh    @ 262144   : 262144
//   woutp  @ 524288   : 16384
//   biasI  @ 540672   : 4096
//   numb   @ 544768   : 512
//   denb   @ 545280   : 512
//   statec @ 545792   : 131072
//   hh     @ 1048576  : 33554432   (packed f16 h history, both dirs)
//   gatex  @ 34603008 : 33554432   (one 128-step chunk of x-gates, f16)
//   feats  @ 34603008 : 8388608    (overlays gatex; written after last lstm)
// ---------------------------------------------------------------------------
extern "C" void kernel_launch(void* const* d_in, const int* in_sizes, int n_in,
                              void* d_out, int out_size, void* d_ws, size_t ws_size,
                              hipStream_t stream)
{
  const int* sentence = (const int*)d_in[0];
  const int* tags = (const int*)d_in[1];
  const float* embed = (const float*)d_in[2];
  const float* Wihf = (const float*)d_in[3];
  const float* Whhf = (const float*)d_in[4];
  const float* bihf = (const float*)d_in[5];
  const float* bhhf = (const float*)d_in[6];
  const float* Wihb = (const float*)d_in[7];
  const float* Whhb = (const float*)d_in[8];
  const float* bihb = (const float*)d_in[9];
  const float* bhhb = (const float*)d_in[10];
  const float* Wout = (const float*)d_in[11];
  const float* bout = (const float*)d_in[12];
  const float* trans = (const float*)d_in[13];
  const float* h0 = (const float*)d_in[14];
  const float* c0 = (const float*)d_in[15];
  float* out = (float*)d_out;

  char* ws = (char*)d_ws;
  uint* wihI = (uint*)(ws + 0);
  uint* whh = (uint*)(ws + 262144);
  uint* woutp = (uint*)(ws + 524288);
  float* biasI = (float*)(ws + 540672);
  float* numb = (float*)(ws + 544768);
  float* denb = (float*)(ws + 545280);
  float* statec = (float*)(ws + 545792);
  uint* hh = (uint*)(ws + 1048576);
  uint* gatex = (uint*)(ws + 34603008);
  float* feats = (float*)(ws + 34603008);

  hipLaunchKernelGGL(prep_kernel, dim3(532), dim3(256), 0, stream,
                     Wihf, Whhf, bihf, bhhf, Wihb, Whhb, bihb, bhhb, Wout,
                     wihI, whh, woutp, biasI);
  for (int c = 0; c < 4; ++c) {
    hipLaunchKernelGGL(gemmx_kernel, dim3(1024), dim3(256), 0, stream,
                       sentence, embed, wihI, biasI, gatex, c);
    hipLaunchKernelGGL(lstm_kernel, dim3(256), dim3(256), 0, stream,
                       gatex, whh, h0, c0, statec, hh, c);
  }
  hipLaunchKernelGGL(outproj_kernel, dim3(8192), dim3(256), 0, stream,
                     hh, woutp, bout, feats);
  hipLaunchKernelGGL(crf_num_kernel, dim3(128), dim3(64), 0, stream,
                     tags, feats, trans, numb);
  hipLaunchKernelGGL(crf_den_kernel, dim3(128), dim3(64), 0, stream,
                     feats, trans, denb);
  hipLaunchKernelGGL(final_kernel, dim3(1), dim3(128), 0, stream,
                     numb, denb, out);
}

// Round 6
// 652.077 us; speedup vs baseline: 1.7554x; 1.0294x over previous
//
#include <hip/hip_runtime.h>

typedef unsigned int uint;
typedef __fp16 half2_t __attribute__((ext_vector_type(2)));
typedef __fp16 half8_t __attribute__((ext_vector_type(8)));
typedef float floatx4 __attribute__((ext_vector_type(4)));

#define SEQ 512
#define BATCH 128
#define HID 128
#define NTAG 32
#define START_TAG 30
#define END_TAG 31

__device__ __forceinline__ float fdot2(uint a, uint b, float c) {
  return __builtin_amdgcn_fdot2(__builtin_bit_cast(half2_t, a),
                                __builtin_bit_cast(half2_t, b), c, false);
}
__device__ __forceinline__ uint packh2(float a, float b) {
  half2_t h = __builtin_amdgcn_cvt_pkrtz(a, b);
  return __builtin_bit_cast(uint, h);
}
__device__ __forceinline__ float frcp(float x) { return __builtin_amdgcn_rcpf(x); }
__device__ __forceinline__ float fsig(float x) { return frcp(1.f + __expf(-x)); }
__device__ __forceinline__ float ftanh(float x) { return 1.f - 2.f * frcp(1.f + __expf(2.f * x)); }
__device__ __forceinline__ float fexp2(float x) { return __builtin_amdgcn_exp2f(x); }
__device__ __forceinline__ float flog2(float x) { return __builtin_amdgcn_logf(x); }

// ---------------------------------------------------------------------------
// prep:
//  wihI[d][n=4m+q][128k] f16 rows (gate-interleaved for MFMA B / lstm uint2)
//  whh [d][g=q*128+m][64dw] f16x2 (for lstm dot2)
//  woutp (outproj), biasI[d][n=4m+q] = b_ih+b_hh
// ---------------------------------------------------------------------------
__global__ __launch_bounds__(256) void prep_kernel(
    const float* __restrict__ Wihf, const float* __restrict__ Whhf,
    const float* __restrict__ bihf, const float* __restrict__ bhhf,
    const float* __restrict__ Wihb, const float* __restrict__ Whhb,
    const float* __restrict__ bihb, const float* __restrict__ bhhb,
    const float* __restrict__ Wout,
    uint* __restrict__ wihI, uint* __restrict__ whh,
    uint* __restrict__ woutp, float* __restrict__ biasI)
{
  int idx = blockIdx.x * 256 + threadIdx.x;
  if (idx < 65536) {  // wihI, gate-interleaved rows
    int d = idx >> 15, rem = idx & 32767;
    int n = rem >> 6, dw = rem & 63;
    int m = n >> 2, q = n & 3;
    int g = q * 128 + m;
    const float* W = d ? Wihb : Wihf;
    wihI[idx] = packh2(W[g * 128 + 2 * dw], W[g * 128 + 2 * dw + 1]);
  }
  int i2 = idx - 65536;
  if (i2 >= 0 && i2 < 65536) {  // whh
    int d = i2 >> 15, rem = i2 & 32767;
    int g = rem >> 6, dw = rem & 63;
    const float* W = d ? Whhb : Whhf;
    whh[i2] = packh2(W[g * 128 + 2 * dw], W[g * 128 + 2 * dw + 1]);
  }
  int i3 = idx - 131072;
  if (i3 >= 0 && i3 < 4096) {  // woutp
    int k = i3 >> 7, dw = i3 & 127;
    float a, b2;
    if (dw < 64) { a = Wout[k * 256 + 2 * dw]; b2 = Wout[k * 256 + 2 * dw + 1]; }
    else { int j = dw - 64; a = Wout[k * 256 + 128 + 2 * j]; b2 = Wout[k * 256 + 128 + 2 * j + 1]; }
    woutp[i3] = packh2(a, b2);
  }
  int i4 = idx - 135168;
  if (i4 >= 0 && i4 < 1024) {  // biasI (interleaved)
    int d = i4 >> 9, n = i4 & 511;
    int g = (n & 3) * 128 + (n >> 2);
    biasI[i4] = d ? (bihb[g] + bhhb[g]) : (bihf[g] + bhhf[g]);
  }
}

// ---------------------------------------------------------------------------
// gemmx (MFMA): per (chunk,dir): C[16384 rows=(tl,b)][512 gates n=4m+q]
//   = embed[tok] (f32->f16) . wihI^T, +bias, stored f16.
// ---------------------------------------------------------------------------
__global__ __launch_bounds__(256, 2) void gemmx_kernel(
    const int* __restrict__ sentence, const float* __restrict__ embed,
    const uint* __restrict__ wihI, const float* __restrict__ biasI,
    uint* __restrict__ gatex, int chunk)
{
  int blk = blockIdx.x;
  int tl = blk & 127, nb = (blk >> 7) & 3, d = blk >> 9;
  int t = chunk * 128 + tl;
  int s = d ? (511 - t) : t;
  __shared__ int tok[128];
  int tid = threadIdx.x;
  if (tid < 128) tok[tid] = sentence[tid * SEQ + s];
  __syncthreads();

  int w = tid >> 6, lane = tid & 63;
  int q = lane >> 4, r = lane & 15;
  int wr = w >> 1, wc = w & 1;
  int r0 = wr * 64;
  int c0 = nb * 128 + wc * 64;

  floatx4 acc[4][4];
#pragma unroll
  for (int i = 0; i < 4; ++i)
#pragma unroll
    for (int j = 0; j < 4; ++j) acc[i][j] = (floatx4){0.f, 0.f, 0.f, 0.f};

  const float4* aptr[4];
#pragma unroll
  for (int i = 0; i < 4; ++i)
    aptr[i] = (const float4*)(embed + (size_t)tok[r0 + i * 16 + r] * HID) + q * 2;
  const uint4* bptr[4];
#pragma unroll
  for (int j = 0; j < 4; ++j)
    bptr[j] = (const uint4*)(wihI + ((size_t)d * 512 + c0 + j * 16 + r) * 64) + q;

#pragma unroll
  for (int kc = 0; kc < 4; ++kc) {
    half8_t af[4], bf[4];
#pragma unroll
    for (int i = 0; i < 4; ++i) {
      float4 x0 = aptr[i][kc * 8];
      float4 x1 = aptr[i][kc * 8 + 1];
      uint4 u;
      u.x = packh2(x0.x, x0.y); u.y = packh2(x0.z, x0.w);
      u.z = packh2(x1.x, x1.y); u.w = packh2(x1.z, x1.w);
      af[i] = __builtin_bit_cast(half8_t, u);
    }
#pragma unroll
    for (int j = 0; j < 4; ++j)
      bf[j] = __builtin_bit_cast(half8_t, bptr[j][kc * 4]);
#pragma unroll
    for (int i = 0; i < 4; ++i)
#pragma unroll
      for (int j = 0; j < 4; ++j)
        acc[i][j] = __builtin_amdgcn_mfma_f32_16x16x32_f16(af[i], bf[j], acc[i][j], 0, 0, 0);
  }

  __fp16* gat = ((__fp16*)gatex) + (size_t)d * 16384 * 512;
#pragma unroll
  for (int j = 0; j < 4; ++j) {
    int n = c0 + j * 16 + r;
    float bb = biasI[d * 512 + n];
#pragma unroll
    for (int i = 0; i < 4; ++i) {
      int rb = r0 + i * 16 + q * 4;
#pragma unroll
      for (int reg = 0; reg < 4; ++reg) {
        float v = acc[i][j][reg] + bb;
        gat[((size_t)(tl * 128 + rb + reg)) * 512 + n] = (__fp16)v;
      }
    }
  }
}

// ---------------------------------------------------------------------------
// LSTM recurrence, h-weights only (32 uint4 = 128 VGPRs/thread). One WG per
// (d,b); 128 steps per launch (chunk). h history in LDS (fp16, direct b16
// writes -> no shfl in the write path), flushed to hh once per chunk.
// ---------------------------------------------------------------------------
__global__ __launch_bounds__(256, 1) void lstm_kernel(
    const uint* __restrict__ gatex, const uint* __restrict__ whh,
    const float* __restrict__ h0, const float* __restrict__ c0,
    float* __restrict__ statec, uint* __restrict__ hh, int chunk)
{
  const int wg = blockIdx.x;
  const int d = wg >> 7, b = wg & 127;
  const int tid = threadIdx.x;
  const int w = tid >> 6, lane = tid & 63;
  const int hp = lane >> 5, r = lane & 31;
  const int m = w * 32 + r;

  __shared__ __align__(16) __fp16 hist[128][128];

  const uint4* wh4 = (const uint4*)(whh + (size_t)d * 512 * 64);
  uint4 wreg[4][8];
#pragma unroll
  for (int q = 0; q < 4; ++q) {
    const uint4* row = wh4 + (q * 128 + m) * 16 + hp * 8;
#pragma unroll
    for (int i = 0; i < 8; ++i) wreg[q][i] = row[i];
  }

  float c = (chunk == 0) ? c0[(size_t)(d * 128 + b) * 128 + m]
                         : statec[(size_t)(d * 128 + b) * 128 + m];

  if (tid < 64) {
    uint* h127 = (uint*)&hist[127][0];
    if (chunk == 0) {
      float2 hv = ((const float2*)(h0 + (size_t)(d * 128 + b) * 128))[tid];
      h127[tid] = packh2(hv.x, hv.y);
    } else {
      int sprev = d ? (511 - (chunk * 128 - 1)) : (chunk * 128 - 1);
      h127[tid] = hh[((size_t)(d * 512 + sprev) * 128 + b) * 64 + tid];
    }
  }
  const uint* gx0 = gatex + (size_t)d * 4194304 + (size_t)b * 256 + 2 * m;
  uint2 gx = *(const uint2*)(gx0);
  __syncthreads();

  for (int tl = 0; tl < 128; ++tl) {
    uint2 gxn = gx;
    if (tl < 127) gxn = *(const uint2*)(gx0 + (size_t)(tl + 1) * 32768);

    float a0 = 0.f, a1 = 0.f, a2 = 0.f, a3 = 0.f;
    const uint4* z4 = (const uint4*)(&hist[(tl + 127) & 127][hp * 64]);
#pragma unroll
    for (int i = 0; i < 8; ++i) {
      uint4 z = z4[i];
      a0 = fdot2(z.x, wreg[0][i].x, a0);
      a0 = fdot2(z.y, wreg[0][i].y, a0);
      a0 = fdot2(z.z, wreg[0][i].z, a0);
      a0 = fdot2(z.w, wreg[0][i].w, a0);
      a1 = fdot2(z.x, wreg[1][i].x, a1);
      a1 = fdot2(z.y, wreg[1][i].y, a1);
      a1 = fdot2(z.z, wreg[1][i].z, a1);
      a1 = fdot2(z.w, wreg[1][i].w, a1);
      a2 = fdot2(z.x, wreg[2][i].x, a2);
      a2 = fdot2(z.y, wreg[2][i].y, a2);
      a2 = fdot2(z.z, wreg[2][i].z, a2);
      a2 = fdot2(z.w, wreg[2][i].w, a2);
      a3 = fdot2(z.x, wreg[3][i].x, a3);
      a3 = fdot2(z.y, wreg[3][i].y, a3);
      a3 = fdot2(z.z, wreg[3][i].z, a3);
      a3 = fdot2(z.w, wreg[3][i].w, a3);
    }
    a0 += __shfl_xor(a0, 32);
    a1 += __shfl_xor(a1, 32);
    a2 += __shfl_xor(a2, 32);
    a3 += __shfl_xor(a3, 32);

    half2_t g01 = __builtin_bit_cast(half2_t, gx.x);
    half2_t g23 = __builtin_bit_cast(half2_t, gx.y);
    a0 += (float)g01[0];
    a1 += (float)g01[1];
    a2 += (float)g23[0];
    a3 += (float)g23[1];

    float ig = fsig(a0);
    float fg = fsig(a1);
    float gg = ftanh(a2);
    float og = fsig(a3);
    c = fg * c + ig * gg;
    float hv = og * ftanh(c);

    if (hp == 0) hist[tl][m] = (__fp16)hv;  // direct b16 write, no shuffle
    gx = gxn;
    __syncthreads();
  }

  statec[(size_t)(d * 128 + b) * 128 + m] = c;

  int base = chunk * 128;
  for (int i = tid; i < 2048; i += 256) {
    int sl = i >> 4, q4 = i & 15;
    int s = d ? (511 - (base + sl)) : (base + sl);
    *(uint4*)(&hh[((size_t)(d * 512 + s) * 128 + b) * 64 + q4 * 4]) =
        *(const uint4*)((const uint*)&hist[sl][0] + q4 * 4);
  }
}

// ---------------------------------------------------------------------------
// Output projection: feats[b,s,k] = [hf|hb] . Wout[k] + bout[k]
// ---------------------------------------------------------------------------
__global__ __launch_bounds__(256) void outproj_kernel(
    const uint* __restrict__ hh, const uint* __restrict__ woutp,
    const float* __restrict__ bout, float* __restrict__ feats)
{
  __shared__ __align__(16) uint4 zrow[8][32];
  __shared__ __align__(16) uint4 wlds[32][32];
  int tid = threadIdx.x;
  for (int j = tid; j < 1024; j += 256) {
    int k = j >> 5, i = j & 31;
    wlds[i][k] = ((const uint4*)woutp)[j];
  }
  int rl = tid >> 5, q = tid & 31;
  int row = blockIdx.x * 8 + rl;
  int b = row >> 9, s = row & 511;
  const uint4* hf4 = (const uint4*)(hh + ((size_t)s * BATCH + b) * 64);
  const uint4* hb4 = (const uint4*)(hh + ((size_t)(SEQ + s) * BATCH + b) * 64);
  zrow[rl][q] = (q < 16) ? hf4[q] : hb4[q - 16];
  __syncthreads();
  int k = q;
  float acc = bout[k];
#pragma unroll
  for (int i = 0; i < 32; ++i) {
    uint4 z = zrow[rl][i];
    uint4 wv = wlds[i][k];
    acc = fdot2(z.x, wv.x, acc);
    acc = fdot2(z.y, wv.y, acc);
    acc = fdot2(z.z, wv.z, acc);
    acc = fdot2(z.w, wv.w, acc);
  }
  feats[(size_t)row * 32 + k] = acc;
}

// ---------------------------------------------------------------------------
// CRF numerator
// ---------------------------------------------------------------------------
__global__ __launch_bounds__(64) void crf_num_kernel(
    const int* __restrict__ tags, const float* __restrict__ feats,
    const float* __restrict__ trans, float* __restrict__ num)
{
  int b = blockIdx.x, l = threadIdx.x;
  const int* tb = tags + b * SEQ;
  float acc = 0.f;
  for (int s = l; s < SEQ; s += 64) {
    int tg = tb[s];
    int pv = (s == 0) ? START_TAG : tb[s - 1];
    acc += trans[pv * NTAG + tg] + feats[((size_t)b * SEQ + s) * NTAG + tg];
  }
#pragma unroll
  for (int msk = 1; msk < 64; msk <<= 1) acc += __shfl_xor(acc, msk);
  if (l == 0) num[b] = acc + trans[tb[SEQ - 1] * NTAG + END_TAG];
}

// ---------------------------------------------------------------------------
// CRF denominator v3: exp-domain linear recurrence. v_{t+1} = (M^T v) * 2^f.
// The 2^f factors are computed in the prefetch ring (off critical chain);
// the per-step chain is just shfl-gather + fma + half-merge + mul.
// Renorm every 8 steps via exact power-of-2 exponent extraction
// (growth ~2^5/step -> 2^40 per block, well inside f32 range).
// ---------------------------------------------------------------------------
__global__ __launch_bounds__(64) void crf_den_kernel(
    const float* __restrict__ feats, const float* __restrict__ trans,
    float* __restrict__ den)
{
  const float L2E = 1.4426950408889634f, LN2 = 0.6931471805599453f;
  int b = blockIdx.x, l = threadIdx.x;
  int k = l & 31, hp = l >> 5;
  // pT[p] = 2^(T[k][hp*16+p]*L2E); the START column underflows to exactly 0
  // (correct: that transition is impossible); row k=END is all ~0 -> v[END]=0.
  float pT[16];
#pragma unroll
  for (int p = 0; p < 16; ++p) pT[p] = fexp2(trans[k * NTAG + hp * 16 + p] * L2E);
  float pEnd = fexp2(trans[k * NTAG + END_TAG] * L2E);
  const float* fb = feats + (size_t)b * SEQ * NTAG;

  // exact init (matches reference step 0 incl. the -1e4 background terms):
  // alpha1[k] = -1e4 + ln(1 + sum_p e^T[k][p]) + f0[k]
  float sT = 0.f;
#pragma unroll
  for (int p = 0; p < 16; ++p) sT += pT[p];
  sT += __shfl_xor(sT, 32);
  float v = (1.f + sT) * fexp2(fb[k] * L2E);
  float L = -10000.f * L2E;

  float ring[8];
#pragma unroll
  for (int j = 0; j < 8; ++j) ring[j] = fexp2(fb[(1 + j) * NTAG + k] * L2E);

  for (int tt = 0; tt < 64; ++tt) {
#pragma unroll
    for (int j = 0; j < 8; ++j) {
      int t = 1 + tt * 8 + j;
      if (t <= 511) {
        float pf = ring[j];
        float fnext = (t + 8 <= 511) ? fb[(t + 8) * NTAG + k] : 0.f;
        float s0 = 0.f, s1 = 0.f, s2 = 0.f, s3 = 0.f;
#pragma unroll
        for (int p = 0; p < 16; p += 4) {
          s0 = fmaf(__shfl(v, hp * 16 + p + 0), pT[p + 0], s0);
          s1 = fmaf(__shfl(v, hp * 16 + p + 1), pT[p + 1], s1);
          s2 = fmaf(__shfl(v, hp * 16 + p + 2), pT[p + 2], s2);
          s3 = fmaf(__shfl(v, hp * 16 + p + 3), pT[p + 3], s3);
        }
        float sm = (s0 + s1) + (s2 + s3);
        sm += __shfl_xor(sm, 32);
        v = sm * pf;
        ring[j] = fexp2(fnext * L2E);
      }
    }
    // exact renorm: divide all v by 2^(e-127) of lane0's v (k=0, always >0)
    uint ub = (uint)__builtin_amdgcn_readfirstlane(
        (int)__builtin_bit_cast(uint, v));
    int e = (int)((ub >> 23) & 255u);
    L += (float)(e - 127);
    float scale = __builtin_bit_cast(float, (uint)((254 - e) << 23));
    v *= scale;
  }
  float wv = v * pEnd;
#pragma unroll
  for (int msk = 1; msk <= 16; msk <<= 1) wv += __shfl_xor(wv, msk);
  if (l == 0) den[b] = (L + flog2(wv)) * LN2;
}

__global__ __launch_bounds__(128) void final_kernel(
    const float* __restrict__ num, const float* __restrict__ den,
    float* __restrict__ out)
{
  int tid = threadIdx.x;
  float v = num[tid] - den[tid];
#pragma unroll
  for (int msk = 1; msk < 64; msk <<= 1) v += __shfl_xor(v, msk);
  __shared__ float tmp[2];
  if ((tid & 63) == 0) tmp[tid >> 6] = v;
  __syncthreads();
  if (tid == 0) out[0] = (tmp[0] + tmp[1]) * (1.f / 128.f);
}

// ---------------------------------------------------------------------------
// Workspace layout (bytes) — same ~65 MB footprint as R5:
//   wihI   @ 0        : 262144
//   whh    @ 262144   : 262144
//   woutp  @ 524288   : 16384
//   biasI  @ 540672   : 4096
//   numb   @ 544768   : 512
//   denb   @ 545280   : 512
//   statec @ 545792   : 131072
//   hh     @ 1048576  : 33554432   (packed f16 h history, both dirs)
//   gatex  @ 34603008 : 33554432   (one 128-step chunk of x-gates, f16)
//   feats  @ 34603008 : 8388608    (overlays gatex; written after last lstm)
// ---------------------------------------------------------------------------
extern "C" void kernel_launch(void* const* d_in, const int* in_sizes, int n_in,
                              void* d_out, int out_size, void* d_ws, size_t ws_size,
                              hipStream_t stream)
{
  const int* sentence = (const int*)d_in[0];
  const int* tags = (const int*)d_in[1];
  const float* embed = (const float*)d_in[2];
  const float* Wihf = (const float*)d_in[3];
  const float* Whhf = (const float*)d_in[4];
  const float* bihf = (const float*)d_in[5];
  const float* bhhf = (const float*)d_in[6];
  const float* Wihb = (const float*)d_in[7];
  const float* Whhb = (const float*)d_in[8];
  const float* bihb = (const float*)d_in[9];
  const float* bhhb = (const float*)d_in[10];
  const float* Wout = (const float*)d_in[11];
  const float* bout = (const float*)d_in[12];
  const float* trans = (const float*)d_in[13];
  const float* h0 = (const float*)d_in[14];
  const float* c0 = (const float*)d_in[15];
  float* out = (float*)d_out;

  char* ws = (char*)d_ws;
  uint* wihI = (uint*)(ws + 0);
  uint* whh = (uint*)(ws + 262144);
  uint* woutp = (uint*)(ws + 524288);
  float* biasI = (float*)(ws + 540672);
  float* numb = (float*)(ws + 544768);
  float* denb = (float*)(ws + 545280);
  float* statec = (float*)(ws + 545792);
  uint* hh = (uint*)(ws + 1048576);
  uint* gatex = (uint*)(ws + 34603008);
  float* feats = (float*)(ws + 34603008);

  hipLaunchKernelGGL(prep_kernel, dim3(532), dim3(256), 0, stream,
                     Wihf, Whhf, bihf, bhhf, Wihb, Whhb, bihb, bhhb, Wout,
                     wihI, whh, woutp, biasI);
  for (int c = 0; c < 4; ++c) {
    hipLaunchKernelGGL(gemmx_kernel, dim3(1024), dim3(256), 0, stream,
                       sentence, embed, wihI, biasI, gatex, c);
    hipLaunchKernelGGL(lstm_kernel, dim3(256), dim3(256), 0, stream,
                       gatex, whh, h0, c0, statec, hh, c);
  }
  hipLaunchKernelGGL(outproj_kernel, dim3(8192), dim3(256), 0, stream,
                     hh, woutp, bout, feats);
  hipLaunchKernelGGL(crf_num_kernel, dim3(128), dim3(64), 0, stream,
                     tags, feats, trans, numb);
  hipLaunchKernelGGL(crf_den_kernel, dim3(128), dim3(64), 0, stream,
                     feats, trans, denb);
  hipLaunchKernelGGL(final_kernel, dim3(1), dim3(128), 0, stream,
                     numb, denb, out);
}

// Round 8
// 581.747 us; speedup vs baseline: 1.9676x; 1.1209x over previous
//
#include <hip/hip_runtime.h>

typedef unsigned int uint;
typedef __fp16 half2_t __attribute__((ext_vector_type(2)));
typedef __fp16 half8_t __attribute__((ext_vector_type(8)));
typedef float floatx4 __attribute__((ext_vector_type(4)));

#define SEQ 512
#define BATCH 128
#define HID 128
#define NTAG 32
#define START_TAG 30
#define END_TAG 31

__device__ __forceinline__ float fdot2(uint a, uint b, float c) {
  return __builtin_amdgcn_fdot2(__builtin_bit_cast(half2_t, a),
                                __builtin_bit_cast(half2_t, b), c, false);
}
__device__ __forceinline__ uint packh2(float a, float b) {
  half2_t h = __builtin_amdgcn_cvt_pkrtz(a, b);
  return __builtin_bit_cast(uint, h);
}
__device__ __forceinline__ float frcp(float x) { return __builtin_amdgcn_rcpf(x); }
__device__ __forceinline__ float fsig(float x) { return frcp(1.f + __expf(-x)); }
__device__ __forceinline__ float ftanh(float x) { return 1.f - 2.f * frcp(1.f + __expf(2.f * x)); }
__device__ __forceinline__ float fexp2(float x) { return __builtin_amdgcn_exp2f(x); }
__device__ __forceinline__ float flog2(float x) { return __builtin_amdgcn_logf(x); }

// ---------------------------------------------------------------------------
// prep (unchanged from R6)
// ---------------------------------------------------------------------------
__global__ __launch_bounds__(256) void prep_kernel(
    const float* __restrict__ Wihf, const float* __restrict__ Whhf,
    const float* __restrict__ bihf, const float* __restrict__ bhhf,
    const float* __restrict__ Wihb, const float* __restrict__ Whhb,
    const float* __restrict__ bihb, const float* __restrict__ bhhb,
    const float* __restrict__ Wout,
    uint* __restrict__ wihI, uint* __restrict__ whh,
    uint* __restrict__ woutp, float* __restrict__ biasI)
{
  int idx = blockIdx.x * 256 + threadIdx.x;
  if (idx < 65536) {
    int d = idx >> 15, rem = idx & 32767;
    int n = rem >> 6, dw = rem & 63;
    int m = n >> 2, q = n & 3;
    int g = q * 128 + m;
    const float* W = d ? Wihb : Wihf;
    wihI[idx] = packh2(W[g * 128 + 2 * dw], W[g * 128 + 2 * dw + 1]);
  }
  int i2 = idx - 65536;
  if (i2 >= 0 && i2 < 65536) {
    int d = i2 >> 15, rem = i2 & 32767;
    int g = rem >> 6, dw = rem & 63;
    const float* W = d ? Whhb : Whhf;
    whh[i2] = packh2(W[g * 128 + 2 * dw], W[g * 128 + 2 * dw + 1]);
  }
  int i3 = idx - 131072;
  if (i3 >= 0 && i3 < 4096) {
    int k = i3 >> 7, dw = i3 & 127;
    float a, b2;
    if (dw < 64) { a = Wout[k * 256 + 2 * dw]; b2 = Wout[k * 256 + 2 * dw + 1]; }
    else { int j = dw - 64; a = Wout[k * 256 + 128 + 2 * j]; b2 = Wout[k * 256 + 128 + 2 * j + 1]; }
    woutp[i3] = packh2(a, b2);
  }
  int i4 = idx - 135168;
  if (i4 >= 0 && i4 < 1024) {
    int d = i4 >> 9, n = i4 & 511;
    int g = (n & 3) * 128 + (n >> 2);
    biasI[i4] = d ? (bihb[g] + bhhb[g]) : (bihf[g] + bhhf[g]);
  }
}

// ---------------------------------------------------------------------------
// gemmx (unchanged from R6)
// ---------------------------------------------------------------------------
__global__ __launch_bounds__(256, 2) void gemmx_kernel(
    const int* __restrict__ sentence, const float* __restrict__ embed,
    const uint* __restrict__ wihI, const float* __restrict__ biasI,
    uint* __restrict__ gatex, int chunk)
{
  int blk = blockIdx.x;
  int tl = blk & 127, nb = (blk >> 7) & 3, d = blk >> 9;
  int t = chunk * 128 + tl;
  int s = d ? (511 - t) : t;
  __shared__ int tok[128];
  int tid = threadIdx.x;
  if (tid < 128) tok[tid] = sentence[tid * SEQ + s];
  __syncthreads();

  int w = tid >> 6, lane = tid & 63;
  int q = lane >> 4, r = lane & 15;
  int wr = w >> 1, wc = w & 1;
  int r0 = wr * 64;
  int c0 = nb * 128 + wc * 64;

  floatx4 acc[4][4];
#pragma unroll
  for (int i = 0; i < 4; ++i)
#pragma unroll
    for (int j = 0; j < 4; ++j) acc[i][j] = (floatx4){0.f, 0.f, 0.f, 0.f};

  const float4* aptr[4];
#pragma unroll
  for (int i = 0; i < 4; ++i)
    aptr[i] = (const float4*)(embed + (size_t)tok[r0 + i * 16 + r] * HID) + q * 2;
  const uint4* bptr[4];
#pragma unroll
  for (int j = 0; j < 4; ++j)
    bptr[j] = (const uint4*)(wihI + ((size_t)d * 512 + c0 + j * 16 + r) * 64) + q;

#pragma unroll
  for (int kc = 0; kc < 4; ++kc) {
    half8_t af[4], bf[4];
#pragma unroll
    for (int i = 0; i < 4; ++i) {
      float4 x0 = aptr[i][kc * 8];
      float4 x1 = aptr[i][kc * 8 + 1];
      uint4 u;
      u.x = packh2(x0.x, x0.y); u.y = packh2(x0.z, x0.w);
      u.z = packh2(x1.x, x1.y); u.w = packh2(x1.z, x1.w);
      af[i] = __builtin_bit_cast(half8_t, u);
    }
#pragma unroll
    for (int j = 0; j < 4; ++j)
      bf[j] = __builtin_bit_cast(half8_t, bptr[j][kc * 4]);
#pragma unroll
    for (int i = 0; i < 4; ++i)
#pragma unroll
      for (int j = 0; j < 4; ++j)
        acc[i][j] = __builtin_amdgcn_mfma_f32_16x16x32_f16(af[i], bf[j], acc[i][j], 0, 0, 0);
  }

  __fp16* gat = ((__fp16*)gatex) + (size_t)d * 16384 * 512;
#pragma unroll
  for (int j = 0; j < 4; ++j) {
    int n = c0 + j * 16 + r;
    float bb = biasI[d * 512 + n];
#pragma unroll
    for (int i = 0; i < 4; ++i) {
      int rb = r0 + i * 16 + q * 4;
#pragma unroll
      for (int reg = 0; reg < 4; ++reg) {
        float v = acc[i][j][reg] + bb;
        gat[((size_t)(tl * 128 + rb + reg)) * 512 + n] = (__fp16)v;
      }
    }
  }
}

// ---------------------------------------------------------------------------
// LSTM recurrence (unchanged from R6)
// ---------------------------------------------------------------------------
__global__ __launch_bounds__(256, 1) void lstm_kernel(
    const uint* __restrict__ gatex, const uint* __restrict__ whh,
    const float* __restrict__ h0, const float* __restrict__ c0,
    float* __restrict__ statec, uint* __restrict__ hh, int chunk)
{
  const int wg = blockIdx.x;
  const int d = wg >> 7, b = wg & 127;
  const int tid = threadIdx.x;
  const int w = tid >> 6, lane = tid & 63;
  const int hp = lane >> 5, r = lane & 31;
  const int m = w * 32 + r;

  __shared__ __align__(16) __fp16 hist[128][128];

  const uint4* wh4 = (const uint4*)(whh + (size_t)d * 512 * 64);
  uint4 wreg[4][8];
#pragma unroll
  for (int q = 0; q < 4; ++q) {
    const uint4* row = wh4 + (q * 128 + m) * 16 + hp * 8;
#pragma unroll
    for (int i = 0; i < 8; ++i) wreg[q][i] = row[i];
  }

  float c = (chunk == 0) ? c0[(size_t)(d * 128 + b) * 128 + m]
                         : statec[(size_t)(d * 128 + b) * 128 + m];

  if (tid < 64) {
    uint* h127 = (uint*)&hist[127][0];
    if (chunk == 0) {
      float2 hv = ((const float2*)(h0 + (size_t)(d * 128 + b) * 128))[tid];
      h127[tid] = packh2(hv.x, hv.y);
    } else {
      int sprev = d ? (511 - (chunk * 128 - 1)) : (chunk * 128 - 1);
      h127[tid] = hh[((size_t)(d * 512 + sprev) * 128 + b) * 64 + tid];
    }
  }
  const uint* gx0 = gatex + (size_t)d * 4194304 + (size_t)b * 256 + 2 * m;
  uint2 gx = *(const uint2*)(gx0);
  __syncthreads();

  for (int tl = 0; tl < 128; ++tl) {
    uint2 gxn = gx;
    if (tl < 127) gxn = *(const uint2*)(gx0 + (size_t)(tl + 1) * 32768);

    float a0 = 0.f, a1 = 0.f, a2 = 0.f, a3 = 0.f;
    const uint4* z4 = (const uint4*)(&hist[(tl + 127) & 127][hp * 64]);
#pragma unroll
    for (int i = 0; i < 8; ++i) {
      uint4 z = z4[i];
      a0 = fdot2(z.x, wreg[0][i].x, a0);
      a0 = fdot2(z.y, wreg[0][i].y, a0);
      a0 = fdot2(z.z, wreg[0][i].z, a0);
      a0 = fdot2(z.w, wreg[0][i].w, a0);
      a1 = fdot2(z.x, wreg[1][i].x, a1);
      a1 = fdot2(z.y, wreg[1][i].y, a1);
      a1 = fdot2(z.z, wreg[1][i].z, a1);
      a1 = fdot2(z.w, wreg[1][i].w, a1);
      a2 = fdot2(z.x, wreg[2][i].x, a2);
      a2 = fdot2(z.y, wreg[2][i].y, a2);
      a2 = fdot2(z.z, wreg[2][i].z, a2);
      a2 = fdot2(z.w, wreg[2][i].w, a2);
      a3 = fdot2(z.x, wreg[3][i].x, a3);
      a3 = fdot2(z.y, wreg[3][i].y, a3);
      a3 = fdot2(z.z, wreg[3][i].z, a3);
      a3 = fdot2(z.w, wreg[3][i].w, a3);
    }
    a0 += __shfl_xor(a0, 32);
    a1 += __shfl_xor(a1, 32);
    a2 += __shfl_xor(a2, 32);
    a3 += __shfl_xor(a3, 32);

    half2_t g01 = __builtin_bit_cast(half2_t, gx.x);
    half2_t g23 = __builtin_bit_cast(half2_t, gx.y);
    a0 += (float)g01[0];
    a1 += (float)g01[1];
    a2 += (float)g23[0];
    a3 += (float)g23[1];

    float ig = fsig(a0);
    float fg = fsig(a1);
    float gg = ftanh(a2);
    float og = fsig(a3);
    c = fg * c + ig * gg;
    float hv = og * ftanh(c);

    if (hp == 0) hist[tl][m] = (__fp16)hv;
    gx = gxn;
    __syncthreads();
  }

  statec[(size_t)(d * 128 + b) * 128 + m] = c;

  int base = chunk * 128;
  for (int i = tid; i < 2048; i += 256) {
    int sl = i >> 4, q4 = i & 15;
    int s = d ? (511 - (base + sl)) : (base + sl);
    *(uint4*)(&hh[((size_t)(d * 512 + s) * 128 + b) * 64 + q4 * 4]) =
        *(const uint4*)((const uint*)&hist[sl][0] + q4 * 4);
  }
}

// ---------------------------------------------------------------------------
// Output projection (unchanged from R6)
// ---------------------------------------------------------------------------
__global__ __launch_bounds__(256) void outproj_kernel(
    const uint* __restrict__ hh, const uint* __restrict__ woutp,
    const float* __restrict__ bout, float* __restrict__ feats)
{
  __shared__ __align__(16) uint4 zrow[8][32];
  __shared__ __align__(16) uint4 wlds[32][32];
  int tid = threadIdx.x;
  for (int j = tid; j < 1024; j += 256) {
    int k = j >> 5, i = j & 31;
    wlds[i][k] = ((const uint4*)woutp)[j];
  }
  int rl = tid >> 5, q = tid & 31;
  int row = blockIdx.x * 8 + rl;
  int b = row >> 9, s = row & 511;
  const uint4* hf4 = (const uint4*)(hh + ((size_t)s * BATCH + b) * 64);
  const uint4* hb4 = (const uint4*)(hh + ((size_t)(SEQ + s) * BATCH + b) * 64);
  zrow[rl][q] = (q < 16) ? hf4[q] : hb4[q - 16];
  __syncthreads();
  int k = q;
  float acc = bout[k];
#pragma unroll
  for (int i = 0; i < 32; ++i) {
    uint4 z = zrow[rl][i];
    uint4 wv = wlds[i][k];
    acc = fdot2(z.x, wv.x, acc);
    acc = fdot2(z.y, wv.y, acc);
    acc = fdot2(z.z, wv.z, acc);
    acc = fdot2(z.w, wv.w, acc);
  }
  feats[(size_t)row * 32 + k] = acc;
}

// ---------------------------------------------------------------------------
// CRF numerator (unchanged)
// ---------------------------------------------------------------------------
__global__ __launch_bounds__(64) void crf_num_kernel(
    const int* __restrict__ tags, const float* __restrict__ feats,
    const float* __restrict__ trans, float* __restrict__ num)
{
  int b = blockIdx.x, l = threadIdx.x;
  const int* tb = tags + b * SEQ;
  float acc = 0.f;
  for (int s = l; s < SEQ; s += 64) {
    int tg = tb[s];
    int pv = (s == 0) ? START_TAG : tb[s - 1];
    acc += trans[pv * NTAG + tg] + feats[((size_t)b * SEQ + s) * NTAG + tg];
  }
#pragma unroll
  for (int msk = 1; msk < 64; msk <<= 1) acc += __shfl_xor(acc, msk);
  if (l == 0) num[b] = acc + trans[tb[SEQ - 1] * NTAG + END_TAG];
}

// ---------------------------------------------------------------------------
// CRF stage A: segment matrix products via MFMA.
// Block (b, j): P_j = A_{tend}...A_{tstart}, A_t = diag(2^{f_t*L2E})*Mt,
// Mt[i][p] = 2^{T[i][p]*L2E}. P kept as f16 B-frags; per step: 4x
// mfma_f32_16x16x32_f16 (C=Mt*P), row-scale by 2^f, exact pow2 renorm
// (exponent of lane0's max, accumulated in Lacc), repack via padded LDS.
// Output: segP[b*32+j][i][p] f16 row-major (32x32), segL[b*32+j].
// ---------------------------------------------------------------------------
__global__ __launch_bounds__(64) void crf_seg_kernel(
    const float* __restrict__ feats, const float* __restrict__ trans,
    uint* __restrict__ segP, float* __restrict__ segL)
{
  const float L2E = 1.4426950408889634f;
  int blk = blockIdx.x;
  int b = blk >> 5, j = blk & 31;
  int tstart = 1 + 16 * j;
  int nsteps = (j == 31) ? 15 : 16;
  int lane = threadIdx.x;
  int c = lane & 15, q = lane >> 4;

  // A-frags: Mt rows, A[m=c + rt*16][k=q*8+i]
  half8_t afr[2];
#pragma unroll
  for (int rt = 0; rt < 2; ++rt) {
    const float* trow = trans + (rt * 16 + c) * 32 + q * 8;
    float e[8];
#pragma unroll
    for (int i = 0; i < 8; ++i) e[i] = fexp2(trow[i] * L2E);
    uint4 u;
    u.x = packh2(e[0], e[1]); u.y = packh2(e[2], e[3]);
    u.z = packh2(e[4], e[5]); u.w = packh2(e[6], e[7]);
    afr[rt] = __builtin_bit_cast(half8_t, u);
  }
  // B-frags: identity. B[k=q*8+i][n=ct*16+c]
  half8_t bfr[2];
#pragma unroll
  for (int ct = 0; ct < 2; ++ct) {
    uint4 u;
    uint vals[8];
#pragma unroll
    for (int i = 0; i < 8; ++i)
      vals[i] = ((q * 8 + i) == (ct * 16 + c)) ? 0x3C00u : 0u;
    u.x = vals[0] | (vals[1] << 16);
    u.y = vals[2] | (vals[3] << 16);
    u.z = vals[4] | (vals[5] << 16);
    u.w = vals[6] | (vals[7] << 16);
    bfr[ct] = __builtin_bit_cast(half8_t, u);
  }

  __shared__ __fp16 P16[32 * 36];  // [n][k], k-dim padded to 36

  const float* fb = feats + ((size_t)b * SEQ + tstart) * NTAG;
  float Lacc = 0.f;
  float4 pre0 = *(const float4*)(fb + q * 4);
  float4 pre1 = *(const float4*)(fb + 16 + q * 4);

  for (int s = 0; s < nsteps; ++s) {
    float4 f0 = pre0, f1 = pre1;
    if (s + 1 < nsteps) {
      pre0 = *(const float4*)(fb + (s + 1) * 32 + q * 4);
      pre1 = *(const float4*)(fb + (s + 1) * 32 + 16 + q * 4);
    }
    floatx4 z4 = (floatx4){0.f, 0.f, 0.f, 0.f};
    floatx4 c00 = __builtin_amdgcn_mfma_f32_16x16x32_f16(afr[0], bfr[0], z4, 0, 0, 0);
    floatx4 c01 = __builtin_amdgcn_mfma_f32_16x16x32_f16(afr[0], bfr[1], z4, 0, 0, 0);
    floatx4 c10 = __builtin_amdgcn_mfma_f32_16x16x32_f16(afr[1], bfr[0], z4, 0, 0, 0);
    floatx4 c11 = __builtin_amdgcn_mfma_f32_16x16x32_f16(afr[1], bfr[1], z4, 0, 0, 0);
    float pf0[4], pf1[4];
    pf0[0] = fexp2(f0.x * L2E); pf0[1] = fexp2(f0.y * L2E);
    pf0[2] = fexp2(f0.z * L2E); pf0[3] = fexp2(f0.w * L2E);
    pf1[0] = fexp2(f1.x * L2E); pf1[1] = fexp2(f1.y * L2E);
    pf1[2] = fexp2(f1.z * L2E); pf1[3] = fexp2(f1.w * L2E);
    float v00[4], v01[4], v10[4], v11[4];
#pragma unroll
    for (int rg = 0; rg < 4; ++rg) {
      v00[rg] = c00[rg] * pf0[rg];
      v01[rg] = c01[rg] * pf0[rg];
      v10[rg] = c10[rg] * pf1[rg];
      v11[rg] = c11[rg] * pf1[rg];
    }
    float mx = 0.f;
#pragma unroll
    for (int rg = 0; rg < 4; ++rg)
      mx = fmaxf(mx, fmaxf(fmaxf(v00[rg], v01[rg]), fmaxf(v10[rg], v11[rg])));
    uint ub = (uint)__builtin_amdgcn_readfirstlane((int)__builtin_bit_cast(uint, mx));
    int e = (int)((ub >> 23) & 255u);
    Lacc += (float)(e - 127);
    float sc = __builtin_bit_cast(float, (uint)((254 - e) << 23));

    __syncthreads();
    {
      // write P'[row][col] to P16[n=col][k=row], rows contiguous per quad
      uint2 w;
      w.x = packh2(v00[0] * sc, v00[1] * sc);
      w.y = packh2(v00[2] * sc, v00[3] * sc);
      *(uint2*)(&P16[c * 36 + q * 4]) = w;               // ct0, rows q*4..+3
      w.x = packh2(v10[0] * sc, v10[1] * sc);
      w.y = packh2(v10[2] * sc, v10[3] * sc);
      *(uint2*)(&P16[c * 36 + 16 + q * 4]) = w;          // ct0, rows 16+q*4..
      w.x = packh2(v01[0] * sc, v01[1] * sc);
      w.y = packh2(v01[2] * sc, v01[3] * sc);
      *(uint2*)(&P16[(16 + c) * 36 + q * 4]) = w;        // ct1
      w.x = packh2(v11[0] * sc, v11[1] * sc);
      w.y = packh2(v11[2] * sc, v11[3] * sc);
      *(uint2*)(&P16[(16 + c) * 36 + 16 + q * 4]) = w;
    }
    __syncthreads();
    {
      uint2 lo0 = *(const uint2*)(&P16[c * 36 + q * 8]);
      uint2 hi0 = *(const uint2*)(&P16[c * 36 + q * 8 + 4]);
      uint4 u0; u0.x = lo0.x; u0.y = lo0.y; u0.z = hi0.x; u0.w = hi0.y;
      bfr[0] = __builtin_bit_cast(half8_t, u0);
      uint2 lo1 = *(const uint2*)(&P16[(16 + c) * 36 + q * 8]);
      uint2 hi1 = *(const uint2*)(&P16[(16 + c) * 36 + q * 8 + 4]);
      uint4 u1; u1.x = lo1.x; u1.y = lo1.y; u1.z = hi1.x; u1.w = hi1.y;
      bfr[1] = __builtin_bit_cast(half8_t, u1);
    }
  }
  __syncthreads();
  // transpose out: segP[blk][i][p] = P16[p][i]
  uint* gp = segP + (size_t)blk * 512;
  if (lane < 32) {
    int i = lane;
#pragma unroll
    for (int tp = 0; tp < 16; ++tp) {
      uint lo = (uint)__builtin_bit_cast(unsigned short, P16[(2 * tp) * 36 + i]);
      uint hi = (uint)__builtin_bit_cast(unsigned short, P16[(2 * tp + 1) * 36 + i]);
      gp[i * 16 + tp] = lo | (hi << 16);
    }
  }
  if (lane == 0) segL[blk] = Lacc;
}

// ---------------------------------------------------------------------------
// CRF stage B: per batch, v1 = exact init; then v <- P_j * v for 32 segments
// (f16 rows prefetched from global, 8 bpermute + 8 fdot2 + merge per seg,
// pow2 renorm each seg). den = (L + log2(sum v*2^{T[:,END]})) * ln2.
// ---------------------------------------------------------------------------
__global__ __launch_bounds__(64) void crf_comb_kernel(
    const float* __restrict__ feats, const float* __restrict__ trans,
    const uint* __restrict__ segP, const float* __restrict__ segL,
    float* __restrict__ den)
{
  const float L2E = 1.4426950408889634f, LN2 = 0.6931471805599453f;
  int b = blockIdx.x, l = threadIdx.x;
  int i = l & 31, hp = l >> 5;
  const float* fb = feats + (size_t)b * SEQ * NTAG;

  // exact init v1[i] = (1 + sum_p 2^{T[i][p]L2E}) * 2^{f0[i]L2E}  (START col -> 0)
  float sT = 0.f;
  for (int p = 0; p < 32; ++p) sT += fexp2(trans[i * 32 + p] * L2E);
  float v = (1.f + sT) * fexp2(fb[i] * L2E);
  float L = -10000.f * L2E;

  // pack v into pairs (both lanes of a pair hold the same packed uint)
  float vo = __shfl_xor(v, 1);
  uint pv = (i & 1) ? packh2(vo, v) : packh2(v, vo);

  const uint* gp0 = segP + (size_t)b * 32 * 512 + i * 16 + hp * 8;
  uint4 ra = *(const uint4*)(gp0);
  uint4 rb = *(const uint4*)(gp0 + 4);

  for (int seg = 0; seg < 32; ++seg) {
    uint4 ca = ra, cb = rb;
    if (seg + 1 < 32) {
      ra = *(const uint4*)(gp0 + (seg + 1) * 512);
      rb = *(const uint4*)(gp0 + (seg + 1) * 512 + 4);
    }
    float g0 = __shfl(__builtin_bit_cast(float, pv), hp * 16 + 0);
    float g1 = __shfl(__builtin_bit_cast(float, pv), hp * 16 + 2);
    float g2 = __shfl(__builtin_bit_cast(float, pv), hp * 16 + 4);
    float g3 = __shfl(__builtin_bit_cast(float, pv), hp * 16 + 6);
    float g4 = __shfl(__builtin_bit_cast(float, pv), hp * 16 + 8);
    float g5 = __shfl(__builtin_bit_cast(float, pv), hp * 16 + 10);
    float g6 = __shfl(__builtin_bit_cast(float, pv), hp * 16 + 12);
    float g7 = __shfl(__builtin_bit_cast(float, pv), hp * 16 + 14);
    float acc = 0.f;
    acc = fdot2(__builtin_bit_cast(uint, g0), ca.x, acc);
    acc = fdot2(__builtin_bit_cast(uint, g1), ca.y, acc);
    acc = fdot2(__builtin_bit_cast(uint, g2), ca.z, acc);
    acc = fdot2(__builtin_bit_cast(uint, g3), ca.w, acc);
    acc = fdot2(__builtin_bit_cast(uint, g4), cb.x, acc);
    acc = fdot2(__builtin_bit_cast(uint, g5), cb.y, acc);
    acc = fdot2(__builtin_bit_cast(uint, g6), cb.z, acc);
    acc = fdot2(__builtin_bit_cast(uint, g7), cb.w, acc);
    float sm = acc + __shfl_xor(acc, 32);
    // renorm by exponent of v_new[0] (lane 0)
    uint ub = (uint)__builtin_amdgcn_readfirstlane((int)__builtin_bit_cast(uint, sm));
    int e = (int)((ub >> 23) & 255u);
    L += (float)(e - 127) + segL[b * 32 + seg];
    float sc = __builtin_bit_cast(float, (uint)((254 - e) << 23));
    v = sm * sc;
    float vo2 = __shfl_xor(v, 1);
    pv = (i & 1) ? packh2(vo2, v) : packh2(v, vo2);
  }
  float wv = v * fexp2(trans[i * 32 + END_TAG] * L2E);
#pragma unroll
  for (int msk = 1; msk <= 16; msk <<= 1) wv += __shfl_xor(wv, msk);
  if (l == 0) den[b] = (L + flog2(wv)) * LN2;
}

__global__ __launch_bounds__(128) void final_kernel(
    const float* __restrict__ num, const float* __restrict__ den,
    float* __restrict__ out)
{
  int tid = threadIdx.x;
  float v = num[tid] - den[tid];
#pragma unroll
  for (int msk = 1; msk < 64; msk <<= 1) v += __shfl_xor(v, msk);
  __shared__ float tmp[2];
  if ((tid & 63) == 0) tmp[tid >> 6] = v;
  __syncthreads();
  if (tid == 0) out[0] = (tmp[0] + tmp[1]) * (1.f / 128.f);
}

// ---------------------------------------------------------------------------
// Workspace layout (bytes):
//   wihI   @ 0        : 262144
//   whh    @ 262144   : 262144
//   woutp  @ 524288   : 16384
//   biasI  @ 540672   : 4096
//   numb   @ 544768   : 512
//   denb   @ 545280   : 512
//   statec @ 545792   : 131072
//   hh     @ 1048576  : 33554432   (packed f16 h history, both dirs)
//   gatex  @ 34603008 : 33554432   (one 128-step chunk of x-gates, f16)
//   feats  @ 34603008 : 8388608    (overlays gatex; written after last lstm)
//   segP   @ 42991616 : 8388608    (32x32 f16 segment matrices)
//   segL   @ 51380224 : 16384
//   total ~51.4 MB
// ---------------------------------------------------------------------------
extern "C" void kernel_launch(void* const* d_in, const int* in_sizes, int n_in,
                              void* d_out, int out_size, void* d_ws, size_t ws_size,
                              hipStream_t stream)
{
  const int* sentence = (const int*)d_in[0];
  const int* tags = (const int*)d_in[1];
  const float* embed = (const float*)d_in[2];
  const float* Wihf = (const float*)d_in[3];
  const float* Whhf = (const float*)d_in[4];
  const float* bihf = (const float*)d_in[5];
  const float* bhhf = (const float*)d_in[6];
  const float* Wihb = (const float*)d_in[7];
  const float* Whhb = (const float*)d_in[8];
  const float* bihb = (const float*)d_in[9];
  const float* bhhb = (const float*)d_in[10];
  const float* Wout = (const float*)d_in[11];
  const float* bout = (const float*)d_in[12];
  const float* trans = (const float*)d_in[13];
  const float* h0 = (const float*)d_in[14];
  const float* c0 = (const float*)d_in[15];
  float* out = (float*)d_out;

  char* ws = (char*)d_ws;
  uint* wihI = (uint*)(ws + 0);
  uint* whh = (uint*)(ws + 262144);
  uint* woutp = (uint*)(ws + 524288);
  float* biasI = (float*)(ws + 540672);
  float* numb = (float*)(ws + 544768);
  float* denb = (float*)(ws + 545280);
  float* statec = (float*)(ws + 545792);
  uint* hh = (uint*)(ws + 1048576);
  uint* gatex = (uint*)(ws + 34603008);
  float* feats = (float*)(ws + 34603008);
  uint* segP = (uint*)(ws + 42991616);
  float* segL = (float*)(ws + 51380224);

  hipLaunchKernelGGL(prep_kernel, dim3(532), dim3(256), 0, stream,
                     Wihf, Whhf, bihf, bhhf, Wihb, Whhb, bihb, bhhb, Wout,
                     wihI, whh, woutp, biasI);
  for (int c = 0; c < 4; ++c) {
    hipLaunchKernelGGL(gemmx_kernel, dim3(1024), dim3(256), 0, stream,
                       sentence, embed, wihI, biasI, gatex, c);
    hipLaunchKernelGGL(lstm_kernel, dim3(256), dim3(256), 0, stream,
                       gatex, whh, h0, c0, statec, hh, c);
  }
  hipLaunchKernelGGL(outproj_kernel, dim3(8192), dim3(256), 0, stream,
                     hh, woutp, bout, feats);
  hipLaunchKernelGGL(crf_num_kernel, dim3(128), dim3(64), 0, stream,
                     tags, feats, trans, numb);
  hipLaunchKernelGGL(crf_seg_kernel, dim3(4096), dim3(64), 0, stream,
                     feats, trans, segP, segL);
  hipLaunchKernelGGL(crf_comb_kernel, dim3(128), dim3(64), 0, stream,
                     feats, trans, segP, segL, denb);
  hipLaunchKernelGGL(final_kernel, dim3(1), dim3(128), 0, stream,
                     numb, denb, out);
}

// Round 9
// 581.125 us; speedup vs baseline: 1.9697x; 1.0011x over previous
//
#include <hip/hip_runtime.h>

typedef unsigned int uint;
typedef __fp16 half2_t __attribute__((ext_vector_type(2)));
typedef __fp16 half8_t __attribute__((ext_vector_type(8)));
typedef float floatx4 __attribute__((ext_vector_type(4)));

#define SEQ 512
#define BATCH 128
#define HID 128
#define NTAG 32
#define START_TAG 30
#define END_TAG 31

__device__ __forceinline__ float fdot2(uint a, uint b, float c) {
  return __builtin_amdgcn_fdot2(__builtin_bit_cast(half2_t, a),
                                __builtin_bit_cast(half2_t, b), c, false);
}
__device__ __forceinline__ uint packh2(float a, float b) {
  half2_t h = __builtin_amdgcn_cvt_pkrtz(a, b);
  return __builtin_bit_cast(uint, h);
}
__device__ __forceinline__ float frcp(float x) { return __builtin_amdgcn_rcpf(x); }
__device__ __forceinline__ float fsig(float x) { return frcp(1.f + __expf(-x)); }
__device__ __forceinline__ float ftanh(float x) { return 1.f - 2.f * frcp(1.f + __expf(2.f * x)); }
__device__ __forceinline__ float fexp2(float x) { return __builtin_amdgcn_exp2f(x); }
__device__ __forceinline__ float flog2(float x) { return __builtin_amdgcn_logf(x); }

// ---------------------------------------------------------------------------
// prep (unchanged from R8)
// ---------------------------------------------------------------------------
__global__ __launch_bounds__(256) void prep_kernel(
    const float* __restrict__ Wihf, const float* __restrict__ Whhf,
    const float* __restrict__ bihf, const float* __restrict__ bhhf,
    const float* __restrict__ Wihb, const float* __restrict__ Whhb,
    const float* __restrict__ bihb, const float* __restrict__ bhhb,
    const float* __restrict__ Wout,
    uint* __restrict__ wihI, uint* __restrict__ whh,
    uint* __restrict__ woutp, float* __restrict__ biasI)
{
  int idx = blockIdx.x * 256 + threadIdx.x;
  if (idx < 65536) {
    int d = idx >> 15, rem = idx & 32767;
    int n = rem >> 6, dw = rem & 63;
    int m = n >> 2, q = n & 3;
    int g = q * 128 + m;
    const float* W = d ? Wihb : Wihf;
    wihI[idx] = packh2(W[g * 128 + 2 * dw], W[g * 128 + 2 * dw + 1]);
  }
  int i2 = idx - 65536;
  if (i2 >= 0 && i2 < 65536) {
    int d = i2 >> 15, rem = i2 & 32767;
    int g = rem >> 6, dw = rem & 63;
    const float* W = d ? Whhb : Whhf;
    whh[i2] = packh2(W[g * 128 + 2 * dw], W[g * 128 + 2 * dw + 1]);
  }
  int i3 = idx - 131072;
  if (i3 >= 0 && i3 < 4096) {
    int k = i3 >> 7, dw = i3 & 127;
    float a, b2;
    if (dw < 64) { a = Wout[k * 256 + 2 * dw]; b2 = Wout[k * 256 + 2 * dw + 1]; }
    else { int j = dw - 64; a = Wout[k * 256 + 128 + 2 * j]; b2 = Wout[k * 256 + 128 + 2 * j + 1]; }
    woutp[i3] = packh2(a, b2);
  }
  int i4 = idx - 135168;
  if (i4 >= 0 && i4 < 1024) {
    int d = i4 >> 9, n = i4 & 511;
    int g = (n & 3) * 128 + (n >> 2);
    biasI[i4] = d ? (bihb[g] + bhhb[g]) : (bihf[g] + bhhf[g]);
  }
}

// ---------------------------------------------------------------------------
// gemmx (unchanged from R8)
// ---------------------------------------------------------------------------
__global__ __launch_bounds__(256, 2) void gemmx_kernel(
    const int* __restrict__ sentence, const float* __restrict__ embed,
    const uint* __restrict__ wihI, const float* __restrict__ biasI,
    uint* __restrict__ gatex, int chunk)
{
  int blk = blockIdx.x;
  int tl = blk & 127, nb = (blk >> 7) & 3, d = blk >> 9;
  int t = chunk * 128 + tl;
  int s = d ? (511 - t) : t;
  __shared__ int tok[128];
  int tid = threadIdx.x;
  if (tid < 128) tok[tid] = sentence[tid * SEQ + s];
  __syncthreads();

  int w = tid >> 6, lane = tid & 63;
  int q = lane >> 4, r = lane & 15;
  int wr = w >> 1, wc = w & 1;
  int r0 = wr * 64;
  int c0 = nb * 128 + wc * 64;

  floatx4 acc[4][4];
#pragma unroll
  for (int i = 0; i < 4; ++i)
#pragma unroll
    for (int j = 0; j < 4; ++j) acc[i][j] = (floatx4){0.f, 0.f, 0.f, 0.f};

  const float4* aptr[4];
#pragma unroll
  for (int i = 0; i < 4; ++i)
    aptr[i] = (const float4*)(embed + (size_t)tok[r0 + i * 16 + r] * HID) + q * 2;
  const uint4* bptr[4];
#pragma unroll
  for (int j = 0; j < 4; ++j)
    bptr[j] = (const uint4*)(wihI + ((size_t)d * 512 + c0 + j * 16 + r) * 64) + q;

#pragma unroll
  for (int kc = 0; kc < 4; ++kc) {
    half8_t af[4], bf[4];
#pragma unroll
    for (int i = 0; i < 4; ++i) {
      float4 x0 = aptr[i][kc * 8];
      float4 x1 = aptr[i][kc * 8 + 1];
      uint4 u;
      u.x = packh2(x0.x, x0.y); u.y = packh2(x0.z, x0.w);
      u.z = packh2(x1.x, x1.y); u.w = packh2(x1.z, x1.w);
      af[i] = __builtin_bit_cast(half8_t, u);
    }
#pragma unroll
    for (int j = 0; j < 4; ++j)
      bf[j] = __builtin_bit_cast(half8_t, bptr[j][kc * 4]);
#pragma unroll
    for (int i = 0; i < 4; ++i)
#pragma unroll
      for (int j = 0; j < 4; ++j)
        acc[i][j] = __builtin_amdgcn_mfma_f32_16x16x32_f16(af[i], bf[j], acc[i][j], 0, 0, 0);
  }

  __fp16* gat = ((__fp16*)gatex) + (size_t)d * 16384 * 512;
#pragma unroll
  for (int j = 0; j < 4; ++j) {
    int n = c0 + j * 16 + r;
    float bb = biasI[d * 512 + n];
#pragma unroll
    for (int i = 0; i < 4; ++i) {
      int rb = r0 + i * 16 + q * 4;
#pragma unroll
      for (int reg = 0; reg < 4; ++reg) {
        float v = acc[i][j][reg] + bb;
        gat[((size_t)(tl * 128 + rb + reg)) * 512 + n] = (__fp16)v;
      }
    }
  }
}

// ---------------------------------------------------------------------------
// LSTM recurrence. One WG per (d,b); grid = 256 = 1 block/CU already.
// R9 change: pad LDS to 96 KB so the compiler's occupancy model matches
// reality (1 block/CU, 1 wave/SIMD) and it keeps wreg's 128 VGPRs resident
// instead of re-loading weights from L2 every step (R8: VGPR_Count=84).
// ---------------------------------------------------------------------------
__global__ __launch_bounds__(256, 1) void lstm_kernel(
    const uint* __restrict__ gatex, const uint* __restrict__ whh,
    const float* __restrict__ h0, const float* __restrict__ c0,
    float* __restrict__ statec, uint* __restrict__ hh, int chunk)
{
  const int wg = blockIdx.x;
  const int d = wg >> 7, b = wg & 127;
  const int tid = threadIdx.x;
  const int w = tid >> 6, lane = tid & 63;
  const int hp = lane >> 5, r = lane & 31;
  const int m = w * 32 + r;

  __shared__ __align__(16) __fp16 hist[128][128];   // 32 KB
  __shared__ uint occupancy_pad[16384];             // 64 KB -> 96 KB total
  if (chunk == -12345) occupancy_pad[tid] = (uint)tid;  // never true; keeps pad alive

  const uint4* wh4 = (const uint4*)(whh + (size_t)d * 512 * 64);
  uint4 wreg[4][8];
#pragma unroll
  for (int q = 0; q < 4; ++q) {
    const uint4* row = wh4 + (q * 128 + m) * 16 + hp * 8;
#pragma unroll
    for (int i = 0; i < 8; ++i) wreg[q][i] = row[i];
  }

  float c = (chunk == 0) ? c0[(size_t)(d * 128 + b) * 128 + m]
                         : statec[(size_t)(d * 128 + b) * 128 + m];

  if (tid < 64) {
    uint* h127 = (uint*)&hist[127][0];
    if (chunk == 0) {
      float2 hv = ((const float2*)(h0 + (size_t)(d * 128 + b) * 128))[tid];
      h127[tid] = packh2(hv.x, hv.y);
    } else {
      int sprev = d ? (511 - (chunk * 128 - 1)) : (chunk * 128 - 1);
      h127[tid] = hh[((size_t)(d * 512 + sprev) * 128 + b) * 64 + tid];
    }
  }
  const uint* gx0 = gatex + (size_t)d * 4194304 + (size_t)b * 256 + 2 * m;
  uint2 gx = *(const uint2*)(gx0);
  __syncthreads();

  for (int tl = 0; tl < 128; ++tl) {
    uint2 gxn = gx;
    if (tl < 127) gxn = *(const uint2*)(gx0 + (size_t)(tl + 1) * 32768);

    float a0 = 0.f, a1 = 0.f, a2 = 0.f, a3 = 0.f;
    const uint4* z4 = (const uint4*)(&hist[(tl + 127) & 127][hp * 64]);
#pragma unroll
    for (int i = 0; i < 8; ++i) {
      uint4 z = z4[i];
      a0 = fdot2(z.x, wreg[0][i].x, a0);
      a0 = fdot2(z.y, wreg[0][i].y, a0);
      a0 = fdot2(z.z, wreg[0][i].z, a0);
      a0 = fdot2(z.w, wreg[0][i].w, a0);
      a1 = fdot2(z.x, wreg[1][i].x, a1);
      a1 = fdot2(z.y, wreg[1][i].y, a1);
      a1 = fdot2(z.z, wreg[1][i].z, a1);
      a1 = fdot2(z.w, wreg[1][i].w, a1);
      a2 = fdot2(z.x, wreg[2][i].x, a2);
      a2 = fdot2(z.y, wreg[2][i].y, a2);
      a2 = fdot2(z.z, wreg[2][i].z, a2);
      a2 = fdot2(z.w, wreg[2][i].w, a2);
      a3 = fdot2(z.x, wreg[3][i].x, a3);
      a3 = fdot2(z.y, wreg[3][i].y, a3);
      a3 = fdot2(z.z, wreg[3][i].z, a3);
      a3 = fdot2(z.w, wreg[3][i].w, a3);
    }
    a0 += __shfl_xor(a0, 32);
    a1 += __shfl_xor(a1, 32);
    a2 += __shfl_xor(a2, 32);
    a3 += __shfl_xor(a3, 32);

    half2_t g01 = __builtin_bit_cast(half2_t, gx.x);
    half2_t g23 = __builtin_bit_cast(half2_t, gx.y);
    a0 += (float)g01[0];
    a1 += (float)g01[1];
    a2 += (float)g23[0];
    a3 += (float)g23[1];

    float ig = fsig(a0);
    float fg = fsig(a1);
    float gg = ftanh(a2);
    float og = fsig(a3);
    c = fg * c + ig * gg;
    float hv = og * ftanh(c);

    if (hp == 0) hist[tl][m] = (__fp16)hv;
    gx = gxn;
    __syncthreads();
  }

  statec[(size_t)(d * 128 + b) * 128 + m] = c;

  int base = chunk * 128;
  for (int i = tid; i < 2048; i += 256) {
    int sl = i >> 4, q4 = i & 15;
    int s = d ? (511 - (base + sl)) : (base + sl);
    *(uint4*)(&hh[((size_t)(d * 512 + s) * 128 + b) * 64 + q4 * 4]) =
        *(const uint4*)((const uint*)&hist[sl][0] + q4 * 4);
  }
}

// ---------------------------------------------------------------------------
// Output projection (unchanged from R8)
// ---------------------------------------------------------------------------
__global__ __launch_bounds__(256) void outproj_kernel(
    const uint* __restrict__ hh, const uint* __restrict__ woutp,
    const float* __restrict__ bout, float* __restrict__ feats)
{
  __shared__ __align__(16) uint4 zrow[8][32];
  __shared__ __align__(16) uint4 wlds[32][32];
  int tid = threadIdx.x;
  for (int j = tid; j < 1024; j += 256) {
    int k = j >> 5, i = j & 31;
    wlds[i][k] = ((const uint4*)woutp)[j];
  }
  int rl = tid >> 5, q = tid & 31;
  int row = blockIdx.x * 8 + rl;
  int b = row >> 9, s = row & 511;
  const uint4* hf4 = (const uint4*)(hh + ((size_t)s * BATCH + b) * 64);
  const uint4* hb4 = (const uint4*)(hh + ((size_t)(SEQ + s) * BATCH + b) * 64);
  zrow[rl][q] = (q < 16) ? hf4[q] : hb4[q - 16];
  __syncthreads();
  int k = q;
  float acc = bout[k];
#pragma unroll
  for (int i = 0; i < 32; ++i) {
    uint4 z = zrow[rl][i];
    uint4 wv = wlds[i][k];
    acc = fdot2(z.x, wv.x, acc);
    acc = fdot2(z.y, wv.y, acc);
    acc = fdot2(z.z, wv.z, acc);
    acc = fdot2(z.w, wv.w, acc);
  }
  feats[(size_t)row * 32 + k] = acc;
}

// ---------------------------------------------------------------------------
// CRF numerator (unchanged)
// ---------------------------------------------------------------------------
__global__ __launch_bounds__(64) void crf_num_kernel(
    const int* __restrict__ tags, const float* __restrict__ feats,
    const float* __restrict__ trans, float* __restrict__ num)
{
  int b = blockIdx.x, l = threadIdx.x;
  const int* tb = tags + b * SEQ;
  float acc = 0.f;
  for (int s = l; s < SEQ; s += 64) {
    int tg = tb[s];
    int pv = (s == 0) ? START_TAG : tb[s - 1];
    acc += trans[pv * NTAG + tg] + feats[((size_t)b * SEQ + s) * NTAG + tg];
  }
#pragma unroll
  for (int msk = 1; msk < 64; msk <<= 1) acc += __shfl_xor(acc, msk);
  if (l == 0) num[b] = acc + trans[tb[SEQ - 1] * NTAG + END_TAG];
}

// ---------------------------------------------------------------------------
// CRF stage A (unchanged from R8)
// ---------------------------------------------------------------------------
__global__ __launch_bounds__(64) void crf_seg_kernel(
    const float* __restrict__ feats, const float* __restrict__ trans,
    uint* __restrict__ segP, float* __restrict__ segL)
{
  const float L2E = 1.4426950408889634f;
  int blk = blockIdx.x;
  int b = blk >> 5, j = blk & 31;
  int tstart = 1 + 16 * j;
  int nsteps = (j == 31) ? 15 : 16;
  int lane = threadIdx.x;
  int c = lane & 15, q = lane >> 4;

  half8_t afr[2];
#pragma unroll
  for (int rt = 0; rt < 2; ++rt) {
    const float* trow = trans + (rt * 16 + c) * 32 + q * 8;
    float e[8];
#pragma unroll
    for (int i = 0; i < 8; ++i) e[i] = fexp2(trow[i] * L2E);
    uint4 u;
    u.x = packh2(e[0], e[1]); u.y = packh2(e[2], e[3]);
    u.z = packh2(e[4], e[5]); u.w = packh2(e[6], e[7]);
    afr[rt] = __builtin_bit_cast(half8_t, u);
  }
  half8_t bfr[2];
#pragma unroll
  for (int ct = 0; ct < 2; ++ct) {
    uint4 u;
    uint vals[8];
#pragma unroll
    for (int i = 0; i < 8; ++i)
      vals[i] = ((q * 8 + i) == (ct * 16 + c)) ? 0x3C00u : 0u;
    u.x = vals[0] | (vals[1] << 16);
    u.y = vals[2] | (vals[3] << 16);
    u.z = vals[4] | (vals[5] << 16);
    u.w = vals[6] | (vals[7] << 16);
    bfr[ct] = __builtin_bit_cast(half8_t, u);
  }

  __shared__ __fp16 P16[32 * 36];

  const float* fb = feats + ((size_t)b * SEQ + tstart) * NTAG;
  float Lacc = 0.f;
  float4 pre0 = *(const float4*)(fb + q * 4);
  float4 pre1 = *(const float4*)(fb + 16 + q * 4);

  for (int s = 0; s < nsteps; ++s) {
    float4 f0 = pre0, f1 = pre1;
    if (s + 1 < nsteps) {
      pre0 = *(const float4*)(fb + (s + 1) * 32 + q * 4);
      pre1 = *(const float4*)(fb + (s + 1) * 32 + 16 + q * 4);
    }
    floatx4 z4 = (floatx4){0.f, 0.f, 0.f, 0.f};
    floatx4 c00 = __builtin_amdgcn_mfma_f32_16x16x32_f16(afr[0], bfr[0], z4, 0, 0, 0);
    floatx4 c01 = __builtin_amdgcn_mfma_f32_16x16x32_f16(afr[0], bfr[1], z4, 0, 0, 0);
    floatx4 c10 = __builtin_amdgcn_mfma_f32_16x16x32_f16(afr[1], bfr[0], z4, 0, 0, 0);
    floatx4 c11 = __builtin_amdgcn_mfma_f32_16x16x32_f16(afr[1], bfr[1], z4, 0, 0, 0);
    float pf0[4], pf1[4];
    pf0[0] = fexp2(f0.x * L2E); pf0[1] = fexp2(f0.y * L2E);
    pf0[2] = fexp2(f0.z * L2E); pf0[3] = fexp2(f0.w * L2E);
    pf1[0] = fexp2(f1.x * L2E); pf1[1] = fexp2(f1.y * L2E);
    pf1[2] = fexp2(f1.z * L2E); pf1[3] = fexp2(f1.w * L2E);
    float v00[4], v01[4], v10[4], v11[4];
#pragma unroll
    for (int rg = 0; rg < 4; ++rg) {
      v00[rg] = c00[rg] * pf0[rg];
      v01[rg] = c01[rg] * pf0[rg];
      v10[rg] = c10[rg] * pf1[rg];
      v11[rg] = c11[rg] * pf1[rg];
    }
    float mx = 0.f;
#pragma unroll
    for (int rg = 0; rg < 4; ++rg)
      mx = fmaxf(mx, fmaxf(fmaxf(v00[rg], v01[rg]), fmaxf(v10[rg], v11[rg])));
    uint ub = (uint)__builtin_amdgcn_readfirstlane((int)__builtin_bit_cast(uint, mx));
    int e = (int)((ub >> 23) & 255u);
    Lacc += (float)(e - 127);
    float sc = __builtin_bit_cast(float, (uint)((254 - e) << 23));

    __syncthreads();
    {
      uint2 wv2;
      wv2.x = packh2(v00[0] * sc, v00[1] * sc);
      wv2.y = packh2(v00[2] * sc, v00[3] * sc);
      *(uint2*)(&P16[c * 36 + q * 4]) = wv2;
      wv2.x = packh2(v10[0] * sc, v10[1] * sc);
      wv2.y = packh2(v10[2] * sc, v10[3] * sc);
      *(uint2*)(&P16[c * 36 + 16 + q * 4]) = wv2;
      wv2.x = packh2(v01[0] * sc, v01[1] * sc);
      wv2.y = packh2(v01[2] * sc, v01[3] * sc);
      *(uint2*)(&P16[(16 + c) * 36 + q * 4]) = wv2;
      wv2.x = packh2(v11[0] * sc, v11[1] * sc);
      wv2.y = packh2(v11[2] * sc, v11[3] * sc);
      *(uint2*)(&P16[(16 + c) * 36 + 16 + q * 4]) = wv2;
    }
    __syncthreads();
    {
      uint2 lo0 = *(const uint2*)(&P16[c * 36 + q * 8]);
      uint2 hi0 = *(const uint2*)(&P16[c * 36 + q * 8 + 4]);
      uint4 u0; u0.x = lo0.x; u0.y = lo0.y; u0.z = hi0.x; u0.w = hi0.y;
      bfr[0] = __builtin_bit_cast(half8_t, u0);
      uint2 lo1 = *(const uint2*)(&P16[(16 + c) * 36 + q * 8]);
      uint2 hi1 = *(const uint2*)(&P16[(16 + c) * 36 + q * 8 + 4]);
      uint4 u1; u1.x = lo1.x; u1.y = lo1.y; u1.z = hi1.x; u1.w = hi1.y;
      bfr[1] = __builtin_bit_cast(half8_t, u1);
    }
  }
  __syncthreads();
  uint* gp = segP + (size_t)blk * 512;
  if (lane < 32) {
    int i = lane;
#pragma unroll
    for (int tp = 0; tp < 16; ++tp) {
      uint lo = (uint)__builtin_bit_cast(unsigned short, P16[(2 * tp) * 36 + i]);
      uint hi = (uint)__builtin_bit_cast(unsigned short, P16[(2 * tp + 1) * 36 + i]);
      gp[i * 16 + tp] = lo | (hi << 16);
    }
  }
  if (lane == 0) segL[blk] = Lacc;
}

// ---------------------------------------------------------------------------
// CRF stage B (unchanged from R8)
// ---------------------------------------------------------------------------
__global__ __launch_bounds__(64) void crf_comb_kernel(
    const float* __restrict__ feats, const float* __restrict__ trans,
    const uint* __restrict__ segP, const float* __restrict__ segL,
    float* __restrict__ den)
{
  const float L2E = 1.4426950408889634f, LN2 = 0.6931471805599453f;
  int b = blockIdx.x, l = threadIdx.x;
  int i = l & 31, hp = l >> 5;
  const float* fb = feats + (size_t)b * SEQ * NTAG;

  float sT = 0.f;
  for (int p = 0; p < 32; ++p) sT += fexp2(trans[i * 32 + p] * L2E);
  float v = (1.f + sT) * fexp2(fb[i] * L2E);
  float L = -10000.f * L2E;

  float vo = __shfl_xor(v, 1);
  uint pv = (i & 1) ? packh2(vo, v) : packh2(v, vo);

  const uint* gp0 = segP + (size_t)b * 32 * 512 + i * 16 + hp * 8;
  uint4 ra = *(const uint4*)(gp0);
  uint4 rb = *(const uint4*)(gp0 + 4);

  for (int seg = 0; seg < 32; ++seg) {
    uint4 ca = ra, cb = rb;
    if (seg + 1 < 32) {
      ra = *(const uint4*)(gp0 + (seg + 1) * 512);
      rb = *(const uint4*)(gp0 + (seg + 1) * 512 + 4);
    }
    float g0 = __shfl(__builtin_bit_cast(float, pv), hp * 16 + 0);
    float g1 = __shfl(__builtin_bit_cast(float, pv), hp * 16 + 2);
    float g2 = __shfl(__builtin_bit_cast(float, pv), hp * 16 + 4);
    float g3 = __shfl(__builtin_bit_cast(float, pv), hp * 16 + 6);
    float g4 = __shfl(__builtin_bit_cast(float, pv), hp * 16 + 8);
    float g5 = __shfl(__builtin_bit_cast(float, pv), hp * 16 + 10);
    float g6 = __shfl(__builtin_bit_cast(float, pv), hp * 16 + 12);
    float g7 = __shfl(__builtin_bit_cast(float, pv), hp * 16 + 14);
    float acc = 0.f;
    acc = fdot2(__builtin_bit_cast(uint, g0), ca.x, acc);
    acc = fdot2(__builtin_bit_cast(uint, g1), ca.y, acc);
    acc = fdot2(__builtin_bit_cast(uint, g2), ca.z, acc);
    acc = fdot2(__builtin_bit_cast(uint, g3), ca.w, acc);
    acc = fdot2(__builtin_bit_cast(uint, g4), cb.x, acc);
    acc = fdot2(__builtin_bit_cast(uint, g5), cb.y, acc);
    acc = fdot2(__builtin_bit_cast(uint, g6), cb.z, acc);
    acc = fdot2(__builtin_bit_cast(uint, g7), cb.w, acc);
    float sm = acc + __shfl_xor(acc, 32);
    uint ub = (uint)__builtin_amdgcn_readfirstlane((int)__builtin_bit_cast(uint, sm));
    int e = (int)((ub >> 23) & 255u);
    L += (float)(e - 127) + segL[b * 32 + seg];
    float sc = __builtin_bit_cast(float, (uint)((254 - e) << 23));
    v = sm * sc;
    float vo2 = __shfl_xor(v, 1);
    pv = (i & 1) ? packh2(vo2, v) : packh2(v, vo2);
  }
  float wv = v * fexp2(trans[i * 32 + END_TAG] * L2E);
#pragma unroll
  for (int msk = 1; msk <= 16; msk <<= 1) wv += __shfl_xor(wv, msk);
  if (l == 0) den[b] = (L + flog2(wv)) * LN2;
}

__global__ __launch_bounds__(128) void final_kernel(
    const float* __restrict__ num, const float* __restrict__ den,
    float* __restrict__ out)
{
  int tid = threadIdx.x;
  float v = num[tid] - den[tid];
#pragma unroll
  for (int msk = 1; msk < 64; msk <<= 1) v += __shfl_xor(v, msk);
  __shared__ float tmp[2];
  if ((tid & 63) == 0) tmp[tid >> 6] = v;
  __syncthreads();
  if (tid == 0) out[0] = (tmp[0] + tmp[1]) * (1.f / 128.f);
}

// ---------------------------------------------------------------------------
// Workspace layout (bytes): same as R8 (~51.4 MB)
// ---------------------------------------------------------------------------
extern "C" void kernel_launch(void* const* d_in, const int* in_sizes, int n_in,
                              void* d_out, int out_size, void* d_ws, size_t ws_size,
                              hipStream_t stream)
{
  const int* sentence = (const int*)d_in[0];
  const int* tags = (const int*)d_in[1];
  const float* embed = (const float*)d_in[2];
  const float* Wihf = (const float*)d_in[3];
  const float* Whhf = (const float*)d_in[4];
  const float* bihf = (const float*)d_in[5];
  const float* bhhf = (const float*)d_in[6];
  const float* Wihb = (const float*)d_in[7];
  const float* Whhb = (const float*)d_in[8];
  const float* bihb = (const float*)d_in[9];
  const float* bhhb = (const float*)d_in[10];
  const float* Wout = (const float*)d_in[11];
  const float* bout = (const float*)d_in[12];
  const float* trans = (const float*)d_in[13];
  const float* h0 = (const float*)d_in[14];
  const float* c0 = (const float*)d_in[15];
  float* out = (float*)d_out;

  char* ws = (char*)d_ws;
  uint* wihI = (uint*)(ws + 0);
  uint* whh = (uint*)(ws + 262144);
  uint* woutp = (uint*)(ws + 524288);
  float* biasI = (float*)(ws + 540672);
  float* numb = (float*)(ws + 544768);
  float* denb = (float*)(ws + 545280);
  float* statec = (float*)(ws + 545792);
  uint* hh = (uint*)(ws + 1048576);
  uint* gatex = (uint*)(ws + 34603008);
  float* feats = (float*)(ws + 34603008);
  uint* segP = (uint*)(ws + 42991616);
  float* segL = (float*)(ws + 51380224);

  hipLaunchKernelGGL(prep_kernel, dim3(532), dim3(256), 0, stream,
                     Wihf, Whhf, bihf, bhhf, Wihb, Whhb, bihb, bhhb, Wout,
                     wihI, whh, woutp, biasI);
  for (int c = 0; c < 4; ++c) {
    hipLaunchKernelGGL(gemmx_kernel, dim3(1024), dim3(256), 0, stream,
                       sentence, embed, wihI, biasI, gatex, c);
    hipLaunchKernelGGL(lstm_kernel, dim3(256), dim3(256), 0, stream,
                       gatex, whh, h0, c0, statec, hh, c);
  }
  hipLaunchKernelGGL(outproj_kernel, dim3(8192), dim3(256), 0, stream,
                     hh, woutp, bout, feats);
  hipLaunchKernelGGL(crf_num_kernel, dim3(128), dim3(64), 0, stream,
                     tags, feats, trans, numb);
  hipLaunchKernelGGL(crf_seg_kernel, dim3(4096), dim3(64), 0, stream,
                     feats, trans, segP, segL);
  hipLaunchKernelGGL(crf_comb_kernel, dim3(128), dim3(64), 0, stream,
                     feats, trans, segP, segL, denb);
  hipLaunchKernelGGL(final_kernel, dim3(1), dim3(128), 0, stream,
                     numb, denb, out);
}